// Round 8
// baseline (829.209 us; speedup 1.0000x reference)
//
#include <hip/hip_runtime.h>

// SchNet on MI355X — round 8: padded (64B/counter) atomic arrays to escape the
// contended far-atomic regime (WRITE_SIZE showed atomics write through to the
// shared memory side); k_norm fused into k_edge_prep. Table-based edge MLP,
// fused per-layer kernels retained from round 7.

#define NN 10000
#define EE 320000
#define HH 128
#define GG 50
#define NF 128
#define NL 6
#define TROWS 2048
#define PAD 16          // ints per atomic counter (64 B line)

typedef unsigned short u16;
typedef unsigned int u32;

__device__ __forceinline__ float us2f(u16 u){
  union { float f; u32 i; } v; v.i = ((u32)u) << 16; return v.f;
}
__device__ __forceinline__ u16 f2us(float x){
  union { float f; u32 i; } v; v.f = x;
  u32 r = v.i + 0x7fffu + ((v.i >> 16) & 1u);   // RNE
  return (u16)(r >> 16);
}
__device__ __forceinline__ float ldin(const void* p, int i, int bf){
  return bf ? us2f(((const u16*)p)[i]) : ((const float*)p)[i];
}
__device__ __forceinline__ float sspf(float x){
  return fmaxf(x, 0.f) + __logf(1.f + __expf(-fabsf(x))) - 0.6931472f;
}

// ---------- dtype detection ----------
__global__ void k_dtype(const u32* __restrict__ zraw, const int* __restrict__ ei_raw,
                        int* __restrict__ flags){
  __shared__ int votes[2];
  if(threadIdx.x < 2) votes[threadIdx.x] = 0;
  __syncthreads();
  int v0 = 0, v1 = 0;
  for(int i = threadIdx.x; i < 4096; i += 256){
    u32 w = zraw[i];
    u32 hb = (w >> 8) & 0x7F;
    if(hb >= 0x38 && hb <= 0x41) v0++;
    if(ei_raw[2*i + 1] == 0) v1++;
  }
  atomicAdd(&votes[0], v0); atomicAdd(&votes[1], v1);
  __syncthreads();
  if(threadIdx.x == 0){
    flags[0] = (votes[0] > 2048) ? 1 : 0;
    flags[1] = (votes[1] > 4000) ? 1 : 0;
  }
}

// ---------- weight staging ----------
__global__ void k_prep_weights(
    const void* __restrict__ mlp1_w, const void* __restrict__ mlp1_b,
    const void* __restrict__ mlp2_w, const void* __restrict__ mlp2_b,
    const void* __restrict__ lin1_w, const void* __restrict__ lin2_w,
    const void* __restrict__ lin2_b, const void* __restrict__ lin_w,
    const void* __restrict__ lin_b,  const void* __restrict__ coord_w,
    const void* __restrict__ coord_b, const int* __restrict__ flags,
    float* __restrict__ b1f, float* __restrict__ b2v,
    float* __restrict__ w1t, float* __restrict__ w2t,
    float* __restrict__ l1t, float* __restrict__ l2t,
    float* __restrict__ l2bf, float* __restrict__ lwt,
    float* __restrict__ lbf, float* __restrict__ cwf, float* __restrict__ cbf)
{
  int i = blockIdx.x*256 + threadIdx.x;           // grid exact: NL*NF*NF
  int bf = flags[0];
  if(i < NL*NF){
    b1f[i]  = ldin(mlp1_b, i, bf);
    b2v[i]  = ldin(mlp2_b, i, bf);
    l2bf[i] = ldin(lin2_b, i, bf);
    lbf[i]  = ldin(lin_b,  i, bf);
  }
  if(i < NL*GG*NF){                               // w1t[l][g][f] = mlp1_w[l][f][g]
    int l = i/(GG*NF), rem = i%(GG*NF);
    int g = rem/NF, f = rem%NF;
    w1t[i] = ldin(mlp1_w, (l*NF + f)*GG + g, bf);
  }
  if(i < NL*NF*NF){
    int l = i/(NF*NF), rem = i%(NF*NF);
    int k = rem/NF, f = rem%NF;
    w2t[i] = ldin(mlp2_w, l*NF*NF + f*NF + k, bf);
    l1t[i] = ldin(lin1_w, l*NF*HH + f*HH + k, bf);
    l2t[i] = ldin(lin2_w, l*HH*NF + f*NF + k, bf);
    lwt[i] = ldin(lin_w,  l*HH*HH + f*HH + k, bf);
  }
  if(i < NL*(GG+2*HH)) cwf[i] = ldin(coord_w, i, bf);
  if(i < NL) cbf[i] = ldin(coord_b, i, bf);
}

__global__ void k_init(const void* __restrict__ z, const void* __restrict__ pos_in,
                       const int* __restrict__ flags,
                       float* __restrict__ h, float* __restrict__ pos){
  int i = blockIdx.x*256 + threadIdx.x;           // grid exact: NN*HH
  int bf = flags[0];
  h[i] = ldin(z, i, bf);
  if(i < NN*3) pos[i] = ldin(pos_in, i, bf);
}

// ---------- edge prep (fused ei decode): distances, padded degrees, w_max ----------
__global__ void k_edge_prep(const int* __restrict__ ei_raw, const int* __restrict__ flags,
                            const float* __restrict__ pos,
                            int* __restrict__ eiN, float* __restrict__ wE,
                            int* __restrict__ deg_row, int* __restrict__ col_deg,
                            int* __restrict__ wmaxi){
  int e = blockIdx.x*256 + threadIdx.x;           // grid exact: EE
  int is64 = flags[1];
  int r = is64 ? ei_raw[2*e] : ei_raw[e];
  int c = is64 ? ei_raw[2*(EE+e)] : ei_raw[EE+e];
  eiN[e] = r; eiN[EE+e] = c;
  float dx = pos[r*3+0]-pos[c*3+0];
  float dy = pos[r*3+1]-pos[c*3+1];
  float dz = pos[r*3+2]-pos[c*3+2];
  float w = sqrtf(dx*dx + dy*dy + dz*dz);
  wE[e] = w;
  float wm = w;
  #pragma unroll
  for(int s=32; s>0; s>>=1) wm = fmaxf(wm, __shfl_down(wm, s, 64));
  if((threadIdx.x & 63) == 0) atomicMax(wmaxi, __float_as_int(wm));
  atomicAdd(&deg_row[r*PAD], 1);                  // 64B-padded counters
  atomicAdd(&col_deg[c*PAD], 1);
}

// ---------- fused dual exclusive scan over padded degs ----------
__global__ void k_scan2(const int* __restrict__ col_deg, const int* __restrict__ deg_row,
                        int* __restrict__ col_start, int* __restrict__ col_next,
                        int* __restrict__ row_start, int* __restrict__ row_next){
  __shared__ int part[1024];
  int tid = threadIdx.x;
  const int CH = (NN + 1023)/1024;
  for(int pass=0; pass<2; pass++){
    const int* deg = pass ? deg_row : col_deg;
    int* start = pass ? row_start : col_start;
    int* nxt   = pass ? row_next  : col_next;
    int base = tid*CH;
    int s = 0;
    for(int i=0;i<CH;i++){ int idx=base+i; if(idx<NN) s += deg[idx*PAD]; }
    part[tid] = s;
    __syncthreads();
    for(int off=1; off<1024; off<<=1){
      int v = (tid>=off) ? part[tid-off] : 0;
      __syncthreads();
      part[tid] += v;
      __syncthreads();
    }
    int run = (tid==0) ? 0 : part[tid-1];
    for(int i=0;i<CH;i++){
      int idx = base+i;
      if(idx<NN){ start[idx]=run; nxt[idx*PAD]=run; run += deg[idx*PAD]; }
    }
    if(tid==1023) start[NN] = run;
    __syncthreads();
  }
}

// ---------- fused CSR fill (padded next counters) ----------
__global__ void k_fill(const int* __restrict__ eiN, const float* __restrict__ wE,
                       int* __restrict__ col_next, int* __restrict__ row_next,
                       int* __restrict__ row_s, float* __restrict__ wEs,
                       int* __restrict__ rcol_s, float* __restrict__ rw_s){
  int e = blockIdx.x*256 + threadIdx.x;           // grid exact: EE
  int r = eiN[e], c = eiN[EE+e];
  float w = wE[e];
  int p = atomicAdd(&col_next[c*PAD], 1);
  row_s[p] = r; wEs[p] = w;
  int p2 = atomicAdd(&row_next[r*PAD], 1);
  rcol_s[p2] = c; rw_s[p2] = w;
}

// ---------- build fp32 tables for all layers ----------
__global__ void k_table(const float* __restrict__ w1t, const float* __restrict__ b1f,
                        const float* __restrict__ w2t, const float* __restrict__ b2v,
                        const float* __restrict__ cwf, const int* __restrict__ wmaxi,
                        float* __restrict__ tabG, float* __restrict__ tabS){
  __shared__ float attr[8][64];
  __shared__ float tls[128][9];
  int f = threadIdx.x;                            // 128
  int l = blockIdx.y;
  int r0 = blockIdx.x*8;
  float delta = __int_as_float(*wmaxi) / (float)(TROWS-1);
  for(int idx=f; idx<8*64; idx+=128){
    int r = idx>>6, g = idx&63;
    float w = (float)(r0+r)*delta;
    float d = w - (float)g*(10.f/49.f);
    attr[r][g] = (g < GG) ? __expf(-12.005f*d*d) : 0.f;
  }
  __syncthreads();
  const float* __restrict__ w1 = w1t + l*GG*NF;
  float b1 = b1f[l*NF + f];
  float acc[8];
  #pragma unroll
  for(int r=0;r<8;r++) acc[r] = b1;
  for(int g=0; g<GG; g++){
    float wv = w1[g*NF + f];
    #pragma unroll
    for(int r=0;r<8;r++) acc[r] += attr[r][g]*wv;
  }
  #pragma unroll
  for(int r=0;r<8;r++) tls[f][r] = sspf(acc[r]);
  __syncthreads();
  const float* __restrict__ w2 = w2t + l*NF*NF;
  float b2 = b2v[l*NF + f];
  float acc2[8];
  #pragma unroll
  for(int r=0;r<8;r++) acc2[r] = b2;
  for(int k=0;k<NF;k++){
    float wv = w2[k*NF + f];
    #pragma unroll
    for(int r=0;r<8;r++) acc2[r] += tls[k][r]*wv;
  }
  #pragma unroll
  for(int r=0;r<8;r++){
    float w = (float)(r0+r)*delta;
    float C = 0.5f*(cosf(w*0.3141592653589793f) + 1.f);
    tabG[((size_t)l*TROWS + r0 + r)*NF + f] = acc2[r]*C;
  }
  if(f < 8){
    const float* __restrict__ cwg = cwf + l*(GG+2*HH);
    float s = 0.f;
    for(int g=0; g<GG; g++) s += attr[f][g]*cwg[g];
    tabS[l*TROWS + r0 + f] = s;
  }
}

// ---------- pack tabG into paired bf16: u32 = (G[i][f], G[i+1][f]) ----------
__global__ void k_pack(const float* __restrict__ tabG, u32* __restrict__ tabGb){
  int i = blockIdx.x*256 + threadIdx.x;           // grid exact: NL*TROWS*NF/256
  int row = (i / NF) % TROWS;
  float g0 = tabG[i];
  float g1 = (row < TROWS-1) ? tabG[i + NF] : g0;
  tabGb[i] = (u32)f2us(g0) | ((u32)f2us(g1) << 16);
}

// ---------- fused per-node kernel: xf (blocks 0..NN/8) + nodedot (rest) ----------
__global__ void k_node(const float* __restrict__ h, const float* __restrict__ l1t,
                       const float* __restrict__ cwf, int l,
                       u16* __restrict__ xfb, float* __restrict__ d_r,
                       float* __restrict__ d_c){
  int b = blockIdx.x;                             // grid: NN/8 + NN/4
  if(b < NN/8){
    int f = threadIdx.x & 127;
    int n0 = b*8 + (threadIdx.x >> 7)*4;
    const float* __restrict__ wt = l1t + l*HH*NF;
    float acc[4] = {0.f,0.f,0.f,0.f};
    for(int k=0;k<HH;k++){
      float wv = wt[k*NF + f];
      #pragma unroll
      for(int i=0;i<4;i++) acc[i] += h[(n0+i)*HH + k] * wv;
    }
    #pragma unroll
    for(int i=0;i<4;i++) xfb[(n0+i)*NF + f] = f2us(acc[i]);
  } else {
    int lane = threadIdx.x & 63;
    int n = (b - NN/8)*4 + (threadIdx.x >> 6);
    const float* __restrict__ cw = cwf + l*(GG + 2*HH);
    float h0 = h[n*HH + lane], h1 = h[n*HH + 64 + lane];
    float ar = h0*cw[GG + lane]      + h1*cw[GG + 64 + lane];
    float ac = h0*cw[GG + HH + lane] + h1*cw[GG + HH + 64 + lane];
    #pragma unroll
    for(int s=32; s>0; s>>=1){
      ar += __shfl_down(ar, s, 64);
      ac += __shfl_down(ac, s, 64);
    }
    if(lane == 0){ d_r[n] = ar; d_c[n] = ac; }
  }
}

// ---------- fused aggregation: cfagg (blocks 0..NN/4) + coordagg (rest) ----------
__global__ void k_agg(const int* __restrict__ col_start, const int* __restrict__ row_s,
                      const float* __restrict__ wEs, const u32* __restrict__ xfb32,
                      const u32* __restrict__ tabGb, const int* __restrict__ wmaxi,
                      int l, float* __restrict__ agg,
                      const int* __restrict__ row_start, const int* __restrict__ rcol_s,
                      const float* __restrict__ rw_s, const float* __restrict__ d_r,
                      const float* __restrict__ d_c, const float* __restrict__ tabS,
                      const float* __restrict__ cbf,
                      const float* __restrict__ pA, float* __restrict__ pB){
  int b = blockIdx.x;                             // grid: NN/4 + NN/4
  float invD = (float)(TROWS-1) / __int_as_float(*wmaxi);
  if(b < NN/4){
    int n = b*4 + (threadIdx.x >> 6);
    int q = threadIdx.x & 63;
    const u32* __restrict__ tg = tabGb + (size_t)l*TROWS*NF;
    int p0 = col_start[n], p1 = col_start[n+1];
    float a0=0.f, b0=0.f, a1=0.f, b1=0.f;
    int p = p0;
    for(; p+2 <= p1; p += 2){
      int r0 = row_s[p], r1 = row_s[p+1];
      float t0 = wEs[p]*invD, t1 = wEs[p+1]*invD;
      int i0 = min((int)t0, TROWS-2), i1 = min((int)t1, TROWS-2);
      float fr0 = t0 - (float)i0, fr1 = t1 - (float)i1;
      uint2 pr0 = *(const uint2*)&tg[i0*NF + 2*q];
      uint2 pr1 = *(const uint2*)&tg[i1*NF + 2*q];
      u32 x0 = xfb32[r0*64 + q], x1 = xfb32[r1*64 + q];
      float lo, hi;
      lo = us2f((u16)pr0.x); hi = us2f((u16)(pr0.x>>16));
      a0 += us2f((u16)x0)      *(lo + (hi-lo)*fr0);
      lo = us2f((u16)pr0.y); hi = us2f((u16)(pr0.y>>16));
      b0 += us2f((u16)(x0>>16))*(lo + (hi-lo)*fr0);
      lo = us2f((u16)pr1.x); hi = us2f((u16)(pr1.x>>16));
      a1 += us2f((u16)x1)      *(lo + (hi-lo)*fr1);
      lo = us2f((u16)pr1.y); hi = us2f((u16)(pr1.y>>16));
      b1 += us2f((u16)(x1>>16))*(lo + (hi-lo)*fr1);
    }
    if(p < p1){
      int r0 = row_s[p];
      float t0 = wEs[p]*invD;
      int i0 = min((int)t0, TROWS-2);
      float fr0 = t0 - (float)i0;
      uint2 pr0 = *(const uint2*)&tg[i0*NF + 2*q];
      u32 x0 = xfb32[r0*64 + q];
      float lo, hi;
      lo = us2f((u16)pr0.x); hi = us2f((u16)(pr0.x>>16));
      a0 += us2f((u16)x0)      *(lo + (hi-lo)*fr0);
      lo = us2f((u16)pr0.y); hi = us2f((u16)(pr0.y>>16));
      b0 += us2f((u16)(x0>>16))*(lo + (hi-lo)*fr0);
    }
    float2 r; r.x = a0+a1; r.y = b0+b1;
    *(float2*)&agg[n*NF + 2*q] = r;
  } else {
    int lane = threadIdx.x & 63;
    int n = (b - NN/4)*4 + (threadIdx.x >> 6);
    const float* __restrict__ ts = tabS + l*TROWS;
    float cb = cbf[l] + d_r[n];
    int p0 = row_start[n], p1 = row_start[n+1];
    float px = pA[n*3+0], py = pA[n*3+1], pz = pA[n*3+2];
    float sx=0.f, sy=0.f, sz=0.f;
    for(int p = p0 + lane; p < p1; p += 64){
      int c = rcol_s[p];
      float tf = rw_s[p]*invD;
      int i0 = min((int)tf, TROWS-2);
      float fr = tf - (float)i0;
      float s0 = ts[i0], s1 = ts[i0+1];
      float acc = cb + d_c[c] + s0 + (s1-s0)*fr;
      sx += (px - pA[c*3+0])*acc;
      sy += (py - pA[c*3+1])*acc;
      sz += (pz - pA[c*3+2])*acc;
    }
    #pragma unroll
    for(int s=32; s>0; s>>=1){
      sx += __shfl_down(sx, s, 64);
      sy += __shfl_down(sy, s, 64);
      sz += __shfl_down(sz, s, 64);
    }
    if(lane == 0){
      int cnt = p1 - p0;
      float inv = (cnt > 0) ? 1.f/(float)cnt : 0.f;
      pB[n*3+0] = px + sx*inv;
      pB[n*3+1] = py + sy*inv;
      pB[n*3+2] = pz + sz*inv;
    }
  }
}

// ---------- h += ssp(agg@lin2^T + b) @ lin^T + b ----------
__global__ void k_update(const float* __restrict__ agg, const float* __restrict__ l2t,
                         const float* __restrict__ l2bf, const float* __restrict__ lwt,
                         const float* __restrict__ lbf, int l, float* __restrict__ h){
  __shared__ float sg[HH*12];
  int f = threadIdx.x;
  int n0 = blockIdx.x*8;                          // grid exact: NN/8
  const float* __restrict__ wA = l2t + l*NF*HH;
  float bA = l2bf[l*HH + f];
  float acc[8];
  #pragma unroll
  for(int i=0;i<8;i++) acc[i] = bA;
  for(int k=0;k<NF;k++){
    float wv = wA[k*HH + f];
    #pragma unroll
    for(int i=0;i<8;i++) acc[i] += agg[(n0+i)*NF + k] * wv;
  }
  #pragma unroll
  for(int i=0;i<8;i++) sg[f*12 + i] = sspf(acc[i]);
  __syncthreads();
  const float* __restrict__ wB = lwt + l*HH*HH;
  float bB = lbf[l*HH + f];
  float acc2[8];
  #pragma unroll
  for(int i=0;i<8;i++) acc2[i] = bB;
  for(int k=0;k<HH;k++){
    float wv = wB[k*HH + f];
    #pragma unroll
    for(int i=0;i<8;i++) acc2[i] += sg[k*12 + i] * wv;
  }
  #pragma unroll
  for(int i=0;i<8;i++) h[(n0+i)*HH + f] += acc2[i];
}

__global__ void k_out(const float* __restrict__ pos, const float* __restrict__ h,
                      const int* __restrict__ flags, void* __restrict__ out){
  int i = blockIdx.x*256 + threadIdx.x;           // grid exact: NN*HH
  if(flags[0]){
    u16* o = (u16*)out;
    if(i < NN*3) o[i] = f2us(pos[i]);
    o[NN*3 + i] = f2us(h[i]);
  } else {
    float* o = (float*)out;
    if(i < NN*3) o[i] = pos[i];
    o[NN*3 + i] = h[i];
  }
}

extern "C" void kernel_launch(void* const* d_in, const int* in_sizes, int n_in,
                              void* d_out, int out_size, void* d_ws, size_t ws_size,
                              hipStream_t stream){
  const void* z      = d_in[0];
  const void* pos_in = d_in[1];
  const int*  ei_raw = (const int*)d_in[2];
  const void* mlp1_w = d_in[3];
  const void* mlp1_b = d_in[4];
  const void* mlp2_w = d_in[5];
  const void* mlp2_b = d_in[6];
  const void* lin1_w = d_in[7];
  const void* lin2_w = d_in[8];
  const void* lin2_b = d_in[9];
  const void* lin_w  = d_in[10];
  const void* lin_b  = d_in[11];
  const void* coord_w= d_in[12];
  const void* coord_b= d_in[13];

  float* W = (float*)d_ws;
  float* h    = W; W += NN*HH;
  float* agg  = W; W += NN*NF;
  float* posA = W; W += NN*3;
  float* posB = W; W += NN*3;
  float* d_r  = W; W += NN;
  float* d_c  = W; W += NN;
  float* wE   = W; W += EE;
  float* wEs  = W; W += EE;
  float* rw_s = W; W += EE;
  float* b1f  = W; W += NL*NF;
  float* b2v  = W; W += NL*NF;
  float* w1t  = W; W += NL*GG*NF;
  float* w2t  = W; W += NL*NF*NF;
  float* l1t  = W; W += NL*NF*HH;
  float* l2t  = W; W += NL*HH*NF;
  float* l2bf = W; W += NL*HH;
  float* lwt  = W; W += NL*HH*HH;
  float* lbf  = W; W += NL*HH;
  float* cwf  = W; W += NL*(GG+2*HH);
  float* cbf  = W; W += NL;
  W = (float*)(((uintptr_t)W + 63) & ~(uintptr_t)63);
  float* tabG = W; W += (size_t)NL*TROWS*NF;
  float* tabS = W; W += NL*TROWS;
  u32*  tabGb = (u32*)W; W += (size_t)NL*TROWS*NF;
  u16* xfb = (u16*)W; W += (NN*NF)/2;
  int* deg_row   = (int*)W; W += NN*PAD;          // 64B-padded atomic counters
  int* col_deg   = (int*)W; W += NN*PAD;
  int* col_next  = (int*)W; W += NN*PAD;
  int* row_next  = (int*)W; W += NN*PAD;
  int* col_start = (int*)W; W += NN+1;
  int* row_start = (int*)W; W += NN+1;
  int* row_s     = (int*)W; W += EE;
  int* rcol_s    = (int*)W; W += EE;
  int* eiN       = (int*)W; W += 2*EE;
  int* flags     = (int*)W; W += 2;
  int* wmaxi     = (int*)W; W += 1;

  hipMemsetAsync(deg_row, 0, NN*PAD*sizeof(int), stream);
  hipMemsetAsync(col_deg, 0, NN*PAD*sizeof(int), stream);
  hipMemsetAsync(wmaxi, 0, sizeof(int), stream);

  k_dtype<<<1, 256, 0, stream>>>((const u32*)z, ei_raw, flags);
  k_prep_weights<<<(NL*NF*NF)/256, 256, 0, stream>>>(
      mlp1_w, mlp1_b, mlp2_w, mlp2_b, lin1_w, lin2_w, lin2_b, lin_w, lin_b,
      coord_w, coord_b, flags,
      b1f, b2v, w1t, w2t, l1t, l2t, l2bf, lwt, lbf, cwf, cbf);
  k_init<<<(NN*HH)/256, 256, 0, stream>>>(z, pos_in, flags, h, posA);
  k_edge_prep<<<EE/256, 256, 0, stream>>>(ei_raw, flags, posA, eiN, wE,
                                          deg_row, col_deg, wmaxi);
  k_scan2<<<1, 1024, 0, stream>>>(col_deg, deg_row, col_start, col_next,
                                  row_start, row_next);
  k_fill<<<EE/256, 256, 0, stream>>>(eiN, wE, col_next, row_next,
                                     row_s, wEs, rcol_s, rw_s);
  k_table<<<dim3(TROWS/8, NL), 128, 0, stream>>>(w1t, b1f, w2t, b2v, cwf, wmaxi,
                                                 tabG, tabS);
  k_pack<<<(NL*TROWS*NF)/256, 256, 0, stream>>>(tabG, tabGb);

  float* pA = posA;
  float* pB = posB;
  for(int l=0; l<NL; l++){
    k_node<<<NN/8 + NN/4, 256, 0, stream>>>(h, l1t, cwf, l, xfb, d_r, d_c);
    k_agg<<<NN/4 + NN/4, 256, 0, stream>>>(col_start, row_s, wEs, (const u32*)xfb,
                                           tabGb, wmaxi, l, agg,
                                           row_start, rcol_s, rw_s, d_r, d_c,
                                           tabS, cbf, pA, pB);
    k_update<<<NN/8, 128, 0, stream>>>(agg, l2t, l2bf, lwt, lbf, l, h);
    float* tmp = pA; pA = pB; pB = tmp;
  }
  // NL even -> final pos back in posA
  k_out<<<(NN*HH)/256, 256, 0, stream>>>(pA, h, flags, (void*)d_out);
}

// Round 9
// 735.212 us; speedup vs baseline: 1.1278x; 1.1278x over previous
//
#include <hip/hip_runtime.h>

// SchNet on MI355X — round 9: atomic-free CSR build. Global device-scope
// atomics run at ~4 ops/cyc device-wide (rounds 6-8: 640k atomics == 68 us,
// insensitive to contention fixes) -> replaced with block-private LDS
// histograms (u16-packed) + deterministic counting-sort placement.
// Table-based edge MLP + fused per-layer kernels retained.

#define NN 10000
#define EE 320000
#define HH 128
#define GG 50
#define NF 128
#define NL 6
#define TROWS 2048
#define NB 128          // histogram blocks; EE/NB = 2500 edges each (fits u16)

typedef unsigned short u16;
typedef unsigned int u32;

__device__ __forceinline__ float us2f(u16 u){
  union { float f; u32 i; } v; v.i = ((u32)u) << 16; return v.f;
}
__device__ __forceinline__ u16 f2us(float x){
  union { float f; u32 i; } v; v.f = x;
  u32 r = v.i + 0x7fffu + ((v.i >> 16) & 1u);   // RNE
  return (u16)(r >> 16);
}
__device__ __forceinline__ float ldin(const void* p, int i, int bf){
  return bf ? us2f(((const u16*)p)[i]) : ((const float*)p)[i];
}
__device__ __forceinline__ float sspf(float x){
  return fmaxf(x, 0.f) + __logf(1.f + __expf(-fabsf(x))) - 0.6931472f;
}

// ---------- dtype detection ----------
__global__ void k_dtype(const u32* __restrict__ zraw, const int* __restrict__ ei_raw,
                        int* __restrict__ flags){
  __shared__ int votes[2];
  if(threadIdx.x < 2) votes[threadIdx.x] = 0;
  __syncthreads();
  int v0 = 0, v1 = 0;
  for(int i = threadIdx.x; i < 4096; i += 256){
    u32 w = zraw[i];
    u32 hb = (w >> 8) & 0x7F;
    if(hb >= 0x38 && hb <= 0x41) v0++;
    if(ei_raw[2*i + 1] == 0) v1++;
  }
  atomicAdd(&votes[0], v0); atomicAdd(&votes[1], v1);
  __syncthreads();
  if(threadIdx.x == 0){
    flags[0] = (votes[0] > 2048) ? 1 : 0;
    flags[1] = (votes[1] > 4000) ? 1 : 0;
  }
}

// ---------- weight staging ----------
__global__ void k_prep_weights(
    const void* __restrict__ mlp1_w, const void* __restrict__ mlp1_b,
    const void* __restrict__ mlp2_w, const void* __restrict__ mlp2_b,
    const void* __restrict__ lin1_w, const void* __restrict__ lin2_w,
    const void* __restrict__ lin2_b, const void* __restrict__ lin_w,
    const void* __restrict__ lin_b,  const void* __restrict__ coord_w,
    const void* __restrict__ coord_b, const int* __restrict__ flags,
    float* __restrict__ b1f, float* __restrict__ b2v,
    float* __restrict__ w1t, float* __restrict__ w2t,
    float* __restrict__ l1t, float* __restrict__ l2t,
    float* __restrict__ l2bf, float* __restrict__ lwt,
    float* __restrict__ lbf, float* __restrict__ cwf, float* __restrict__ cbf)
{
  int i = blockIdx.x*256 + threadIdx.x;           // grid exact: NL*NF*NF
  int bf = flags[0];
  if(i < NL*NF){
    b1f[i]  = ldin(mlp1_b, i, bf);
    b2v[i]  = ldin(mlp2_b, i, bf);
    l2bf[i] = ldin(lin2_b, i, bf);
    lbf[i]  = ldin(lin_b,  i, bf);
  }
  if(i < NL*GG*NF){                               // w1t[l][g][f] = mlp1_w[l][f][g]
    int l = i/(GG*NF), rem = i%(GG*NF);
    int g = rem/NF, f = rem%NF;
    w1t[i] = ldin(mlp1_w, (l*NF + f)*GG + g, bf);
  }
  if(i < NL*NF*NF){
    int l = i/(NF*NF), rem = i%(NF*NF);
    int k = rem/NF, f = rem%NF;
    w2t[i] = ldin(mlp2_w, l*NF*NF + f*NF + k, bf);
    l1t[i] = ldin(lin1_w, l*NF*HH + f*HH + k, bf);
    l2t[i] = ldin(lin2_w, l*HH*NF + f*NF + k, bf);
    lwt[i] = ldin(lin_w,  l*HH*HH + f*HH + k, bf);
  }
  if(i < NL*(GG+2*HH)) cwf[i] = ldin(coord_w, i, bf);
  if(i < NL) cbf[i] = ldin(coord_b, i, bf);
}

__global__ void k_init(const void* __restrict__ z, const void* __restrict__ pos_in,
                       const int* __restrict__ flags,
                       float* __restrict__ h, float* __restrict__ pos){
  int i = blockIdx.x*256 + threadIdx.x;           // grid exact: NN*HH
  int bf = flags[0];
  h[i] = ldin(z, i, bf);
  if(i < NN*3) pos[i] = ldin(pos_in, i, bf);
}

// ---------- count: decode ei, distances, LDS histograms (no global atomics) ----------
// u16-packed: hist32[n>>1], low half = even n, high half = odd n. Max count 2500.
__global__ void k_count(const int* __restrict__ ei_raw, const int* __restrict__ flags,
                        const float* __restrict__ pos,
                        int* __restrict__ eiN, float* __restrict__ wE,
                        u32* __restrict__ partR, u32* __restrict__ partC,
                        int* __restrict__ wmaxi){
  __shared__ u32 hr[NN/2];                        // 20 KB
  __shared__ u32 hc[NN/2];                        // 20 KB
  int b = blockIdx.x, tid = threadIdx.x;          // grid: NB x 256
  for(int i=tid; i<NN/2; i+=256){ hr[i]=0; hc[i]=0; }
  __syncthreads();
  int e0 = b*(EE/NB), e1 = e0 + EE/NB;
  int is64 = flags[1];
  float wm = 0.f;
  for(int e = e0 + tid; e < e1; e += 256){
    int r = is64 ? ei_raw[2*e] : ei_raw[e];
    int c = is64 ? ei_raw[2*(EE+e)] : ei_raw[EE+e];
    eiN[e] = r; eiN[EE+e] = c;
    float dx = pos[r*3+0]-pos[c*3+0];
    float dy = pos[r*3+1]-pos[c*3+1];
    float dz = pos[r*3+2]-pos[c*3+2];
    float w = sqrtf(dx*dx + dy*dy + dz*dz);
    wE[e] = w;
    wm = fmaxf(wm, w);
    atomicAdd(&hr[r>>1], (r&1) ? 0x10000u : 1u);
    atomicAdd(&hc[c>>1], (c&1) ? 0x10000u : 1u);
  }
  #pragma unroll
  for(int s=32; s>0; s>>=1) wm = fmaxf(wm, __shfl_down(wm, s, 64));
  if((tid & 63) == 0) atomicMax(wmaxi, __float_as_int(wm));
  __syncthreads();
  for(int i=tid; i<NN/2; i+=256){
    u32 vr = hr[i], vc = hc[i];
    partR[(size_t)b*NN + 2*i]     = vr & 0xFFFFu;
    partR[(size_t)b*NN + 2*i + 1] = vr >> 16;
    partC[(size_t)b*NN + 2*i]     = vc & 0xFFFFu;
    partC[(size_t)b*NN + 2*i + 1] = vc >> 16;
  }
}

// ---------- per-node: partials -> exclusive block-prefixes (in place) + totals ----------
__global__ void k_sumpref(u32* __restrict__ partR, u32* __restrict__ partC,
                          int* __restrict__ degR, int* __restrict__ degC){
  int n = blockIdx.x*256 + threadIdx.x;
  if(n >= NN) return;
  u32 rr = 0, rc = 0;
  for(int b=0; b<NB; b++){
    u32 vr = partR[(size_t)b*NN + n], vc = partC[(size_t)b*NN + n];
    partR[(size_t)b*NN + n] = rr;
    partC[(size_t)b*NN + n] = rc;
    rr += vr; rc += vc;
  }
  degR[n] = (int)rr; degC[n] = (int)rc;
}

// ---------- fused dual exclusive scan over totals ----------
__global__ void k_scan2(const int* __restrict__ col_deg, const int* __restrict__ deg_row,
                        int* __restrict__ col_start, int* __restrict__ row_start){
  __shared__ int part[1024];
  int tid = threadIdx.x;
  const int CH = (NN + 1023)/1024;
  for(int pass=0; pass<2; pass++){
    const int* deg = pass ? deg_row : col_deg;
    int* start = pass ? row_start : col_start;
    int base = tid*CH;
    int s = 0;
    for(int i=0;i<CH;i++){ int idx=base+i; if(idx<NN) s += deg[idx]; }
    part[tid] = s;
    __syncthreads();
    for(int off=1; off<1024; off<<=1){
      int v = (tid>=off) ? part[tid-off] : 0;
      __syncthreads();
      part[tid] += v;
      __syncthreads();
    }
    int run = (tid==0) ? 0 : part[tid-1];
    for(int i=0;i<CH;i++){
      int idx = base+i;
      if(idx<NN){ start[idx]=run; run += deg[idx]; }
    }
    if(tid==1023) start[NN] = run;
    __syncthreads();
  }
}

// ---------- fill: deterministic placement via LDS rank histograms ----------
__global__ void k_fill2(const int* __restrict__ eiN, const float* __restrict__ wE,
                        const int* __restrict__ col_start, const int* __restrict__ row_start,
                        const u32* __restrict__ partR, const u32* __restrict__ partC,
                        int* __restrict__ row_s, float* __restrict__ wEs,
                        int* __restrict__ rcol_s, float* __restrict__ rw_s){
  __shared__ u32 hr[NN/2];                        // 20 KB
  __shared__ u32 hc[NN/2];                        // 20 KB
  int b = blockIdx.x, tid = threadIdx.x;          // grid: NB x 256
  for(int i=tid; i<NN/2; i+=256){ hr[i]=0; hc[i]=0; }
  __syncthreads();
  int e0 = b*(EE/NB), e1 = e0 + EE/NB;
  for(int e = e0 + tid; e < e1; e += 256){
    int r = eiN[e], c = eiN[EE+e];
    float w = wE[e];
    u32 oldc = atomicAdd(&hc[c>>1], (c&1) ? 0x10000u : 1u);
    u32 rkc = (c&1) ? (oldc >> 16) : (oldc & 0xFFFFu);
    int p = col_start[c] + (int)partC[(size_t)b*NN + c] + (int)rkc;
    row_s[p] = r; wEs[p] = w;
    u32 oldr = atomicAdd(&hr[r>>1], (r&1) ? 0x10000u : 1u);
    u32 rkr = (r&1) ? (oldr >> 16) : (oldr & 0xFFFFu);
    int p2 = row_start[r] + (int)partR[(size_t)b*NN + r] + (int)rkr;
    rcol_s[p2] = c; rw_s[p2] = w;
  }
}

// ---------- build fp32 tables for all layers ----------
__global__ void k_table(const float* __restrict__ w1t, const float* __restrict__ b1f,
                        const float* __restrict__ w2t, const float* __restrict__ b2v,
                        const float* __restrict__ cwf, const int* __restrict__ wmaxi,
                        float* __restrict__ tabG, float* __restrict__ tabS){
  __shared__ float attr[8][64];
  __shared__ float tls[128][9];
  int f = threadIdx.x;                            // 128
  int l = blockIdx.y;
  int r0 = blockIdx.x*8;
  float delta = __int_as_float(*wmaxi) / (float)(TROWS-1);
  for(int idx=f; idx<8*64; idx+=128){
    int r = idx>>6, g = idx&63;
    float w = (float)(r0+r)*delta;
    float d = w - (float)g*(10.f/49.f);
    attr[r][g] = (g < GG) ? __expf(-12.005f*d*d) : 0.f;
  }
  __syncthreads();
  const float* __restrict__ w1 = w1t + l*GG*NF;
  float b1 = b1f[l*NF + f];
  float acc[8];
  #pragma unroll
  for(int r=0;r<8;r++) acc[r] = b1;
  for(int g=0; g<GG; g++){
    float wv = w1[g*NF + f];
    #pragma unroll
    for(int r=0;r<8;r++) acc[r] += attr[r][g]*wv;
  }
  #pragma unroll
  for(int r=0;r<8;r++) tls[f][r] = sspf(acc[r]);
  __syncthreads();
  const float* __restrict__ w2 = w2t + l*NF*NF;
  float b2 = b2v[l*NF + f];
  float acc2[8];
  #pragma unroll
  for(int r=0;r<8;r++) acc2[r] = b2;
  for(int k=0;k<NF;k++){
    float wv = w2[k*NF + f];
    #pragma unroll
    for(int r=0;r<8;r++) acc2[r] += tls[k][r]*wv;
  }
  #pragma unroll
  for(int r=0;r<8;r++){
    float w = (float)(r0+r)*delta;
    float C = 0.5f*(cosf(w*0.3141592653589793f) + 1.f);
    tabG[((size_t)l*TROWS + r0 + r)*NF + f] = acc2[r]*C;
  }
  if(f < 8){
    const float* __restrict__ cwg = cwf + l*(GG+2*HH);
    float s = 0.f;
    for(int g=0; g<GG; g++) s += attr[f][g]*cwg[g];
    tabS[l*TROWS + r0 + f] = s;
  }
}

// ---------- pack tabG into paired bf16: u32 = (G[i][f], G[i+1][f]) ----------
__global__ void k_pack(const float* __restrict__ tabG, u32* __restrict__ tabGb){
  int i = blockIdx.x*256 + threadIdx.x;           // grid exact: NL*TROWS*NF/256
  int row = (i / NF) % TROWS;
  float g0 = tabG[i];
  float g1 = (row < TROWS-1) ? tabG[i + NF] : g0;
  tabGb[i] = (u32)f2us(g0) | ((u32)f2us(g1) << 16);
}

// ---------- fused per-node kernel: xf (blocks 0..NN/8) + nodedot (rest) ----------
__global__ void k_node(const float* __restrict__ h, const float* __restrict__ l1t,
                       const float* __restrict__ cwf, int l,
                       u16* __restrict__ xfb, float* __restrict__ d_r,
                       float* __restrict__ d_c){
  int b = blockIdx.x;                             // grid: NN/8 + NN/4
  if(b < NN/8){
    int f = threadIdx.x & 127;
    int n0 = b*8 + (threadIdx.x >> 7)*4;
    const float* __restrict__ wt = l1t + l*HH*NF;
    float acc[4] = {0.f,0.f,0.f,0.f};
    for(int k=0;k<HH;k++){
      float wv = wt[k*NF + f];
      #pragma unroll
      for(int i=0;i<4;i++) acc[i] += h[(n0+i)*HH + k] * wv;
    }
    #pragma unroll
    for(int i=0;i<4;i++) xfb[(n0+i)*NF + f] = f2us(acc[i]);
  } else {
    int lane = threadIdx.x & 63;
    int n = (b - NN/8)*4 + (threadIdx.x >> 6);
    const float* __restrict__ cw = cwf + l*(GG + 2*HH);
    float h0 = h[n*HH + lane], h1 = h[n*HH + 64 + lane];
    float ar = h0*cw[GG + lane]      + h1*cw[GG + 64 + lane];
    float ac = h0*cw[GG + HH + lane] + h1*cw[GG + HH + 64 + lane];
    #pragma unroll
    for(int s=32; s>0; s>>=1){
      ar += __shfl_down(ar, s, 64);
      ac += __shfl_down(ac, s, 64);
    }
    if(lane == 0){ d_r[n] = ar; d_c[n] = ac; }
  }
}

// ---------- fused aggregation: cfagg (blocks 0..NN/4) + coordagg (rest) ----------
__global__ void k_agg(const int* __restrict__ col_start, const int* __restrict__ row_s,
                      const float* __restrict__ wEs, const u32* __restrict__ xfb32,
                      const u32* __restrict__ tabGb, const int* __restrict__ wmaxi,
                      int l, float* __restrict__ agg,
                      const int* __restrict__ row_start, const int* __restrict__ rcol_s,
                      const float* __restrict__ rw_s, const float* __restrict__ d_r,
                      const float* __restrict__ d_c, const float* __restrict__ tabS,
                      const float* __restrict__ cbf,
                      const float* __restrict__ pA, float* __restrict__ pB){
  int b = blockIdx.x;                             // grid: NN/4 + NN/4
  float invD = (float)(TROWS-1) / __int_as_float(*wmaxi);
  if(b < NN/4){
    int n = b*4 + (threadIdx.x >> 6);
    int q = threadIdx.x & 63;
    const u32* __restrict__ tg = tabGb + (size_t)l*TROWS*NF;
    int p0 = col_start[n], p1 = col_start[n+1];
    float a0=0.f, b0=0.f, a1=0.f, b1=0.f;
    int p = p0;
    for(; p+2 <= p1; p += 2){
      int r0 = row_s[p], r1 = row_s[p+1];
      float t0 = wEs[p]*invD, t1 = wEs[p+1]*invD;
      int i0 = min((int)t0, TROWS-2), i1 = min((int)t1, TROWS-2);
      float fr0 = t0 - (float)i0, fr1 = t1 - (float)i1;
      uint2 pr0 = *(const uint2*)&tg[i0*NF + 2*q];
      uint2 pr1 = *(const uint2*)&tg[i1*NF + 2*q];
      u32 x0 = xfb32[r0*64 + q], x1 = xfb32[r1*64 + q];
      float lo, hi;
      lo = us2f((u16)pr0.x); hi = us2f((u16)(pr0.x>>16));
      a0 += us2f((u16)x0)      *(lo + (hi-lo)*fr0);
      lo = us2f((u16)pr0.y); hi = us2f((u16)(pr0.y>>16));
      b0 += us2f((u16)(x0>>16))*(lo + (hi-lo)*fr0);
      lo = us2f((u16)pr1.x); hi = us2f((u16)(pr1.x>>16));
      a1 += us2f((u16)x1)      *(lo + (hi-lo)*fr1);
      lo = us2f((u16)pr1.y); hi = us2f((u16)(pr1.y>>16));
      b1 += us2f((u16)(x1>>16))*(lo + (hi-lo)*fr1);
    }
    if(p < p1){
      int r0 = row_s[p];
      float t0 = wEs[p]*invD;
      int i0 = min((int)t0, TROWS-2);
      float fr0 = t0 - (float)i0;
      uint2 pr0 = *(const uint2*)&tg[i0*NF + 2*q];
      u32 x0 = xfb32[r0*64 + q];
      float lo, hi;
      lo = us2f((u16)pr0.x); hi = us2f((u16)(pr0.x>>16));
      a0 += us2f((u16)x0)      *(lo + (hi-lo)*fr0);
      lo = us2f((u16)pr0.y); hi = us2f((u16)(pr0.y>>16));
      b0 += us2f((u16)(x0>>16))*(lo + (hi-lo)*fr0);
    }
    float2 r; r.x = a0+a1; r.y = b0+b1;
    *(float2*)&agg[n*NF + 2*q] = r;
  } else {
    int lane = threadIdx.x & 63;
    int n = (b - NN/4)*4 + (threadIdx.x >> 6);
    const float* __restrict__ ts = tabS + l*TROWS;
    float cb = cbf[l] + d_r[n];
    int p0 = row_start[n], p1 = row_start[n+1];
    float px = pA[n*3+0], py = pA[n*3+1], pz = pA[n*3+2];
    float sx=0.f, sy=0.f, sz=0.f;
    for(int p = p0 + lane; p < p1; p += 64){
      int c = rcol_s[p];
      float tf = rw_s[p]*invD;
      int i0 = min((int)tf, TROWS-2);
      float fr = tf - (float)i0;
      float s0 = ts[i0], s1 = ts[i0+1];
      float acc = cb + d_c[c] + s0 + (s1-s0)*fr;
      sx += (px - pA[c*3+0])*acc;
      sy += (py - pA[c*3+1])*acc;
      sz += (pz - pA[c*3+2])*acc;
    }
    #pragma unroll
    for(int s=32; s>0; s>>=1){
      sx += __shfl_down(sx, s, 64);
      sy += __shfl_down(sy, s, 64);
      sz += __shfl_down(sz, s, 64);
    }
    if(lane == 0){
      int cnt = p1 - p0;
      float inv = (cnt > 0) ? 1.f/(float)cnt : 0.f;
      pB[n*3+0] = px + sx*inv;
      pB[n*3+1] = py + sy*inv;
      pB[n*3+2] = pz + sz*inv;
    }
  }
}

// ---------- h += ssp(agg@lin2^T + b) @ lin^T + b ----------
__global__ void k_update(const float* __restrict__ agg, const float* __restrict__ l2t,
                         const float* __restrict__ l2bf, const float* __restrict__ lwt,
                         const float* __restrict__ lbf, int l, float* __restrict__ h){
  __shared__ float sg[HH*12];
  int f = threadIdx.x;
  int n0 = blockIdx.x*8;                          // grid exact: NN/8
  const float* __restrict__ wA = l2t + l*NF*HH;
  float bA = l2bf[l*HH + f];
  float acc[8];
  #pragma unroll
  for(int i=0;i<8;i++) acc[i] = bA;
  for(int k=0;k<NF;k++){
    float wv = wA[k*HH + f];
    #pragma unroll
    for(int i=0;i<8;i++) acc[i] += agg[(n0+i)*NF + k] * wv;
  }
  #pragma unroll
  for(int i=0;i<8;i++) sg[f*12 + i] = sspf(acc[i]);
  __syncthreads();
  const float* __restrict__ wB = lwt + l*HH*HH;
  float bB = lbf[l*HH + f];
  float acc2[8];
  #pragma unroll
  for(int i=0;i<8;i++) acc2[i] = bB;
  for(int k=0;k<HH;k++){
    float wv = wB[k*HH + f];
    #pragma unroll
    for(int i=0;i<8;i++) acc2[i] += sg[k*12 + i] * wv;
  }
  #pragma unroll
  for(int i=0;i<8;i++) h[(n0+i)*HH + f] += acc2[i];
}

__global__ void k_out(const float* __restrict__ pos, const float* __restrict__ h,
                      const int* __restrict__ flags, void* __restrict__ out){
  int i = blockIdx.x*256 + threadIdx.x;           // grid exact: NN*HH
  if(flags[0]){
    u16* o = (u16*)out;
    if(i < NN*3) o[i] = f2us(pos[i]);
    o[NN*3 + i] = f2us(h[i]);
  } else {
    float* o = (float*)out;
    if(i < NN*3) o[i] = pos[i];
    o[NN*3 + i] = h[i];
  }
}

extern "C" void kernel_launch(void* const* d_in, const int* in_sizes, int n_in,
                              void* d_out, int out_size, void* d_ws, size_t ws_size,
                              hipStream_t stream){
  const void* z      = d_in[0];
  const void* pos_in = d_in[1];
  const int*  ei_raw = (const int*)d_in[2];
  const void* mlp1_w = d_in[3];
  const void* mlp1_b = d_in[4];
  const void* mlp2_w = d_in[5];
  const void* mlp2_b = d_in[6];
  const void* lin1_w = d_in[7];
  const void* lin2_w = d_in[8];
  const void* lin2_b = d_in[9];
  const void* lin_w  = d_in[10];
  const void* lin_b  = d_in[11];
  const void* coord_w= d_in[12];
  const void* coord_b= d_in[13];

  float* W = (float*)d_ws;
  float* h    = W; W += NN*HH;
  float* agg  = W; W += NN*NF;
  float* posA = W; W += NN*3;
  float* posB = W; W += NN*3;
  float* d_r  = W; W += NN;
  float* d_c  = W; W += NN;
  float* wE   = W; W += EE;
  float* wEs  = W; W += EE;
  float* rw_s = W; W += EE;
  float* b1f  = W; W += NL*NF;
  float* b2v  = W; W += NL*NF;
  float* w1t  = W; W += NL*GG*NF;
  float* w2t  = W; W += NL*NF*NF;
  float* l1t  = W; W += NL*NF*HH;
  float* l2t  = W; W += NL*HH*NF;
  float* l2bf = W; W += NL*HH;
  float* lwt  = W; W += NL*HH*HH;
  float* lbf  = W; W += NL*HH;
  float* cwf  = W; W += NL*(GG+2*HH);
  float* cbf  = W; W += NL;
  W = (float*)(((uintptr_t)W + 63) & ~(uintptr_t)63);
  float* tabG = W; W += (size_t)NL*TROWS*NF;
  float* tabS = W; W += NL*TROWS;
  u32*  tabGb = (u32*)W; W += (size_t)NL*TROWS*NF;
  u16* xfb = (u16*)W; W += (NN*NF)/2;
  u32* partR = (u32*)W; W += (size_t)NB*NN;       // 5.12 MB
  u32* partC = (u32*)W; W += (size_t)NB*NN;       // 5.12 MB
  int* degR      = (int*)W; W += NN;
  int* degC      = (int*)W; W += NN;
  int* col_start = (int*)W; W += NN+1;
  int* row_start = (int*)W; W += NN+1;
  int* row_s     = (int*)W; W += EE;
  int* rcol_s    = (int*)W; W += EE;
  int* eiN       = (int*)W; W += 2*EE;
  int* flags     = (int*)W; W += 2;
  int* wmaxi     = (int*)W; W += 1;

  hipMemsetAsync(wmaxi, 0, sizeof(int), stream);

  k_dtype<<<1, 256, 0, stream>>>((const u32*)z, ei_raw, flags);
  k_prep_weights<<<(NL*NF*NF)/256, 256, 0, stream>>>(
      mlp1_w, mlp1_b, mlp2_w, mlp2_b, lin1_w, lin2_w, lin2_b, lin_w, lin_b,
      coord_w, coord_b, flags,
      b1f, b2v, w1t, w2t, l1t, l2t, l2bf, lwt, lbf, cwf, cbf);
  k_init<<<(NN*HH)/256, 256, 0, stream>>>(z, pos_in, flags, h, posA);
  k_count<<<NB, 256, 0, stream>>>(ei_raw, flags, posA, eiN, wE, partR, partC, wmaxi);
  k_sumpref<<<(NN+255)/256, 256, 0, stream>>>(partR, partC, degR, degC);
  k_scan2<<<1, 1024, 0, stream>>>(degC, degR, col_start, row_start);
  k_fill2<<<NB, 256, 0, stream>>>(eiN, wE, col_start, row_start, partR, partC,
                                  row_s, wEs, rcol_s, rw_s);
  k_table<<<dim3(TROWS/8, NL), 128, 0, stream>>>(w1t, b1f, w2t, b2v, cwf, wmaxi,
                                                 tabG, tabS);
  k_pack<<<(NL*TROWS*NF)/256, 256, 0, stream>>>(tabG, tabGb);

  float* pA = posA;
  float* pB = posB;
  for(int l=0; l<NL; l++){
    k_node<<<NN/8 + NN/4, 256, 0, stream>>>(h, l1t, cwf, l, xfb, d_r, d_c);
    k_agg<<<NN/4 + NN/4, 256, 0, stream>>>(col_start, row_s, wEs, (const u32*)xfb,
                                           tabGb, wmaxi, l, agg,
                                           row_start, rcol_s, rw_s, d_r, d_c,
                                           tabS, cbf, pA, pB);
    k_update<<<NN/8, 128, 0, stream>>>(agg, l2t, l2bf, lwt, lbf, l, h);
    float* tmp = pA; pA = pB; pB = tmp;
  }
  // NL even -> final pos back in posA
  k_out<<<(NN*HH)/256, 256, 0, stream>>>(pA, h, flags, (void*)d_out);
}

// Round 10
// 579.811 us; speedup vs baseline: 1.4301x; 1.2680x over previous
//
#include <hip/hip_runtime.h>

// SchNet on MI355X — round 10: dispatch-count collapse (29 -> 17).
// Inline dtype detection (no flags kernel/memsets), fused init+prep (K1),
// fused fill2+table-pack+node0 (K5), fused update(l)+node(l+1) (k_upnode),
// outputs written in-place by upnode(5)/agg(5) (k_out deleted).
// Table-based edge MLP + atomic-free CSR retained from round 9.

#define NN 10000
#define EE 320000
#define HH 128
#define GG 50
#define NF 128
#define NL 6
#define TROWS 2048
#define NB 128          // histogram blocks; EE/NB = 2500 edges each (fits u16)

typedef unsigned short u16;
typedef unsigned int u32;

__device__ __forceinline__ float us2f(u16 u){
  union { float f; u32 i; } v; v.i = ((u32)u) << 16; return v.f;
}
__device__ __forceinline__ u16 f2us(float x){
  union { float f; u32 i; } v; v.f = x;
  u32 r = v.i + 0x7fffu + ((v.i >> 16) & 1u);   // RNE
  return (u16)(r >> 16);
}
__device__ __forceinline__ float ldin(const void* p, int i, int bf){
  return bf ? us2f(((const u16*)p)[i]) : ((const float*)p)[i];
}
__device__ __forceinline__ float sspf(float x){
  return fmaxf(x, 0.f) + __logf(1.f + __expf(-fabsf(x))) - 0.6931472f;
}
// deterministic inline dtype probes: every wave samples the SAME 256 words,
// so the verdict is identical across all waves/blocks.
__device__ __forceinline__ int detect_bf(const u32* __restrict__ zraw){
  int lane = threadIdx.x & 63;
  int c = 0;
  #pragma unroll
  for(int j=0;j<4;j++){
    u32 w = zraw[lane*4+j];
    u32 hb = (w >> 8) & 0x7F;
    c += (hb >= 0x38 && hb <= 0x41) ? 1 : 0;
  }
  return __popcll(__ballot(c >= 2)) >= 32;
}
__device__ __forceinline__ int detect_i64(const int* __restrict__ ei_raw){
  int lane = threadIdx.x & 63;
  int c = 0;
  #pragma unroll
  for(int j=0;j<4;j++) c += (ei_raw[2*(lane*4+j)+1] == 0) ? 1 : 0;
  return __popcll(__ballot(c >= 3)) >= 32;
}

// ---------- K1: fused init (blocks 0..4999) + weight prep (5000..5383) ----------
__global__ void k_prep(const u32* __restrict__ zraw, const void* __restrict__ pos_in,
    const void* __restrict__ mlp1_w, const void* __restrict__ mlp1_b,
    const void* __restrict__ mlp2_w, const void* __restrict__ mlp2_b,
    const void* __restrict__ lin1_w, const void* __restrict__ lin2_w,
    const void* __restrict__ lin2_b, const void* __restrict__ lin_w,
    const void* __restrict__ lin_b,  const void* __restrict__ coord_w,
    const void* __restrict__ coord_b,
    float* __restrict__ h, float* __restrict__ pos, int* __restrict__ wmaxi,
    float* __restrict__ b1f, float* __restrict__ b2v,
    float* __restrict__ w1t, float* __restrict__ w2t,
    float* __restrict__ l1t, float* __restrict__ l2t,
    float* __restrict__ l2bf, float* __restrict__ lwt,
    float* __restrict__ lbf, float* __restrict__ cwf, float* __restrict__ cbf)
{
  int bf = detect_bf(zraw);
  int b = blockIdx.x;
  if(b < NN*HH/256){
    int i = b*256 + threadIdx.x;
    h[i] = ldin(zraw, i, bf);
    if(i < NN*3) pos[i] = ldin(pos_in, i, bf);
    if(i == 0) *wmaxi = 0;
  } else {
    int i = (b - NN*HH/256)*256 + threadIdx.x;    // < NL*NF*NF
    if(i < NL*NF){
      b1f[i]  = ldin(mlp1_b, i, bf);
      b2v[i]  = ldin(mlp2_b, i, bf);
      l2bf[i] = ldin(lin2_b, i, bf);
      lbf[i]  = ldin(lin_b,  i, bf);
    }
    if(i < NL*GG*NF){                             // w1t[l][g][f]
      int l = i/(GG*NF), rem = i%(GG*NF);
      int g = rem/NF, f = rem%NF;
      w1t[i] = ldin(mlp1_w, (l*NF + f)*GG + g, bf);
    }
    if(i < NL*NF*NF){
      int l = i/(NF*NF), rem = i%(NF*NF);
      int k = rem/NF, f = rem%NF;
      w2t[i] = ldin(mlp2_w, l*NF*NF + f*NF + k, bf);
      l1t[i] = ldin(lin1_w, l*NF*HH + f*HH + k, bf);
      l2t[i] = ldin(lin2_w, l*HH*NF + f*NF + k, bf);
      lwt[i] = ldin(lin_w,  l*HH*HH + f*HH + k, bf);
    }
    if(i < NL*(GG+2*HH)) cwf[i] = ldin(coord_w, i, bf);
    if(i < NL) cbf[i] = ldin(coord_b, i, bf);
  }
}

// ---------- K2: decode ei, distances, LDS histograms (no global atomics) ----------
__global__ void k_count(const int* __restrict__ ei_raw, const float* __restrict__ pos,
                        int* __restrict__ eiN, float* __restrict__ wE,
                        u32* __restrict__ partR, u32* __restrict__ partC,
                        int* __restrict__ wmaxi){
  __shared__ u32 hr[NN/2];
  __shared__ u32 hc[NN/2];
  int is64 = detect_i64(ei_raw);
  int b = blockIdx.x, tid = threadIdx.x;          // grid: NB x 256
  for(int i=tid; i<NN/2; i+=256){ hr[i]=0; hc[i]=0; }
  __syncthreads();
  int e0 = b*(EE/NB), e1 = e0 + EE/NB;
  float wm = 0.f;
  for(int e = e0 + tid; e < e1; e += 256){
    int r = is64 ? ei_raw[2*e] : ei_raw[e];
    int c = is64 ? ei_raw[2*(EE+e)] : ei_raw[EE+e];
    eiN[e] = r; eiN[EE+e] = c;
    float dx = pos[r*3+0]-pos[c*3+0];
    float dy = pos[r*3+1]-pos[c*3+1];
    float dz = pos[r*3+2]-pos[c*3+2];
    float w = sqrtf(dx*dx + dy*dy + dz*dz);
    wE[e] = w;
    wm = fmaxf(wm, w);
    atomicAdd(&hr[r>>1], (r&1) ? 0x10000u : 1u);
    atomicAdd(&hc[c>>1], (c&1) ? 0x10000u : 1u);
  }
  #pragma unroll
  for(int s=32; s>0; s>>=1) wm = fmaxf(wm, __shfl_down(wm, s, 64));
  if((tid & 63) == 0) atomicMax(wmaxi, __float_as_int(wm));
  __syncthreads();
  for(int i=tid; i<NN/2; i+=256){
    u32 vr = hr[i], vc = hc[i];
    partR[(size_t)b*NN + 2*i]     = vr & 0xFFFFu;
    partR[(size_t)b*NN + 2*i + 1] = vr >> 16;
    partC[(size_t)b*NN + 2*i]     = vc & 0xFFFFu;
    partC[(size_t)b*NN + 2*i + 1] = vc >> 16;
  }
}

// ---------- K3: partials -> exclusive block-prefixes + totals ----------
__global__ void k_sumpref(u32* __restrict__ partR, u32* __restrict__ partC,
                          int* __restrict__ degR, int* __restrict__ degC){
  int n = blockIdx.x*256 + threadIdx.x;
  if(n >= NN) return;
  u32 rr = 0, rc = 0;
  for(int b=0; b<NB; b++){
    u32 vr = partR[(size_t)b*NN + n], vc = partC[(size_t)b*NN + n];
    partR[(size_t)b*NN + n] = rr;
    partC[(size_t)b*NN + n] = rc;
    rr += vr; rc += vc;
  }
  degR[n] = (int)rr; degC[n] = (int)rc;
}

// ---------- K4: fused dual exclusive scan ----------
__global__ void k_scan2(const int* __restrict__ col_deg, const int* __restrict__ deg_row,
                        int* __restrict__ col_start, int* __restrict__ row_start){
  __shared__ int part[1024];
  int tid = threadIdx.x;
  const int CH = (NN + 1023)/1024;
  for(int pass=0; pass<2; pass++){
    const int* deg = pass ? deg_row : col_deg;
    int* start = pass ? row_start : col_start;
    int base = tid*CH;
    int s = 0;
    for(int i=0;i<CH;i++){ int idx=base+i; if(idx<NN) s += deg[idx]; }
    part[tid] = s;
    __syncthreads();
    for(int off=1; off<1024; off<<=1){
      int v = (tid>=off) ? part[tid-off] : 0;
      __syncthreads();
      part[tid] += v;
      __syncthreads();
    }
    int run = (tid==0) ? 0 : part[tid-1];
    for(int i=0;i<CH;i++){
      int idx = base+i;
      if(idx<NN){ start[idx]=run; run += deg[idx]; }
    }
    if(tid==1023) start[NN] = run;
    __syncthreads();
  }
}

// ---------- K5: fused CSR fill (0..127) + table build+pack (128..895)
//              + layer-0 node (896..4645) ----------
__global__ void k_setup2(const int* __restrict__ eiN, const float* __restrict__ wE,
                         const int* __restrict__ col_start, const int* __restrict__ row_start,
                         const u32* __restrict__ partR, const u32* __restrict__ partC,
                         int* __restrict__ row_s, float* __restrict__ wEs,
                         int* __restrict__ rcol_s, float* __restrict__ rw_s,
                         const float* __restrict__ w1t, const float* __restrict__ b1f,
                         const float* __restrict__ w2t, const float* __restrict__ b2v,
                         const float* __restrict__ cwf, const int* __restrict__ wmaxi,
                         u32* __restrict__ tabGb, float* __restrict__ tabS,
                         const float* __restrict__ h, const float* __restrict__ l1t,
                         u16* __restrict__ xfb, float* __restrict__ d_r,
                         float* __restrict__ d_c){
  __shared__ u32 smem[NN];                        // 40 KB, aliased per role
  int b = blockIdx.x, t = threadIdx.x;
  if(b < NB){
    // ---- CSR fill via LDS rank histograms ----
    u32* hr = smem;
    u32* hc = smem + NN/2;
    for(int i=t; i<NN/2; i+=256){ hr[i]=0; hc[i]=0; }
    __syncthreads();
    int e0 = b*(EE/NB), e1 = e0 + EE/NB;
    for(int e = e0 + t; e < e1; e += 256){
      int r = eiN[e], c = eiN[EE+e];
      float w = wE[e];
      u32 oldc = atomicAdd(&hc[c>>1], (c&1) ? 0x10000u : 1u);
      u32 rkc = (c&1) ? (oldc >> 16) : (oldc & 0xFFFFu);
      int p = col_start[c] + (int)partC[(size_t)b*NN + c] + (int)rkc;
      row_s[p] = r; wEs[p] = w;
      u32 oldr = atomicAdd(&hr[r>>1], (r&1) ? 0x10000u : 1u);
      u32 rkr = (r&1) ? (oldr >> 16) : (oldr & 0xFFFFu);
      int p2 = row_start[r] + (int)partR[(size_t)b*NN + r] + (int)rkr;
      rcol_s[p2] = c; rw_s[p2] = w;
    }
  } else if(b < NB + NL*128){
    // ---- table: 16 packed rows/block (+1 overlap row for lerp neighbor) ----
    float* attr = (float*)smem;                   // [17][64]
    float* tls  = (float*)smem + 17*64;           // [128][19] (stride 19: odd)
    int lb = b - NB;
    int l = lb >> 7;
    int r0 = (lb & 127)*16;
    int f = t & 127, half = t >> 7;
    float delta = __int_as_float(*wmaxi) / (float)(TROWS-1);
    for(int idx=t; idx<17*64; idx+=256){
      int r = idx >> 6, g = idx & 63;
      int row = min(r0 + r, TROWS-1);
      float w = (float)row*delta;
      float d = w - (float)g*(10.f/49.f);
      attr[idx] = (g < GG) ? __expf(-12.005f*d*d) : 0.f;
    }
    __syncthreads();
    const float* __restrict__ w1 = w1t + l*GG*NF;
    float b1 = b1f[l*NF + f];
    float a1[9];
    #pragma unroll
    for(int r=0;r<9;r++) a1[r] = b1;
    for(int g=0; g<GG; g++){
      float wv = w1[g*NF + f];
      #pragma unroll
      for(int r=0;r<9;r++) a1[r] += attr[(half*8 + r)*64 + g]*wv;
    }
    #pragma unroll
    for(int r=0;r<9;r++) tls[f*19 + half*9 + r] = sspf(a1[r]);
    __syncthreads();
    const float* __restrict__ w2 = w2t + l*NF*NF;
    float b2 = b2v[l*NF + f];
    float a2[9];
    #pragma unroll
    for(int r=0;r<9;r++) a2[r] = b2;
    for(int k=0;k<NF;k++){
      float wv = w2[k*NF + f];
      #pragma unroll
      for(int r=0;r<9;r++) a2[r] += tls[k*19 + half*9 + r]*wv;
    }
    float v[9];
    #pragma unroll
    for(int r=0;r<9;r++){
      int row = min(r0 + half*8 + r, TROWS-1);
      float w = (float)row*delta;
      float C = 0.5f*(cosf(w*0.3141592653589793f) + 1.f);
      v[r] = a2[r]*C;
    }
    #pragma unroll
    for(int j=0;j<8;j++){
      int row = r0 + half*8 + j;
      tabGb[((size_t)l*TROWS + row)*NF + f] = (u32)f2us(v[j]) | ((u32)f2us(v[j+1]) << 16);
    }
    if(t < 16){
      const float* __restrict__ cwg = cwf + l*(GG+2*HH);
      float s = 0.f;
      for(int g=0; g<GG; g++) s += attr[t*64 + g]*cwg[g];
      tabS[l*TROWS + r0 + t] = s;
    }
  } else {
    // ---- layer-0 node: xf (0..1249) + nodedot (1250..3749) ----
    int nb = b - (NB + NL*128);
    if(nb < NN/8){
      int f = t & 127, g = t >> 7;
      int n0 = nb*8 + g*4;
      const float* __restrict__ wt = l1t;         // l=0
      float acc[4] = {0.f,0.f,0.f,0.f};
      for(int k=0;k<HH;k++){
        float wv = wt[k*NF + f];
        #pragma unroll
        for(int i=0;i<4;i++) acc[i] += h[(n0+i)*HH + k]*wv;
      }
      #pragma unroll
      for(int i=0;i<4;i++) xfb[(n0+i)*NF + f] = f2us(acc[i]);
    } else {
      int lane = t & 63;
      int n = (nb - NN/8)*4 + (t >> 6);
      const float* __restrict__ cw = cwf;         // l=0
      float h0 = h[n*HH + lane], h1 = h[n*HH + 64 + lane];
      float ar = h0*cw[GG + lane]      + h1*cw[GG + 64 + lane];
      float ac = h0*cw[GG + HH + lane] + h1*cw[GG + HH + 64 + lane];
      #pragma unroll
      for(int s=32; s>0; s>>=1){
        ar += __shfl_down(ar, s, 64);
        ac += __shfl_down(ac, s, 64);
      }
      if(lane == 0){ d_r[n] = ar; d_c[n] = ac; }
    }
  }
}

// ---------- per-layer: fused aggregation (cfagg + coordagg) ----------
__global__ void k_agg(const int* __restrict__ col_start, const int* __restrict__ row_s,
                      const float* __restrict__ wEs, const u32* __restrict__ xfb32,
                      const u32* __restrict__ tabGb, const int* __restrict__ wmaxi,
                      int l, float* __restrict__ agg,
                      const int* __restrict__ row_start, const int* __restrict__ rcol_s,
                      const float* __restrict__ rw_s, const float* __restrict__ d_r,
                      const float* __restrict__ d_c, const float* __restrict__ tabS,
                      const float* __restrict__ cbf,
                      const float* __restrict__ pA, float* __restrict__ pB,
                      const u32* __restrict__ zraw, void* __restrict__ out){
  int b = blockIdx.x;                             // grid: NN/4 + NN/4
  float invD = (float)(TROWS-1) / __int_as_float(*wmaxi);
  if(b < NN/4){
    int n = b*4 + (threadIdx.x >> 6);
    int q = threadIdx.x & 63;
    const u32* __restrict__ tg = tabGb + (size_t)l*TROWS*NF;
    int p0 = col_start[n], p1 = col_start[n+1];
    float aa[4] = {0.f,0.f,0.f,0.f};
    float bb[4] = {0.f,0.f,0.f,0.f};
    int p = p0;
    for(; p+4 <= p1; p += 4){
      #pragma unroll
      for(int j=0;j<4;j++){
        int r = row_s[p+j];
        float tf = wEs[p+j]*invD;
        int i0 = min((int)tf, TROWS-2);
        float fr = tf - (float)i0;
        uint2 pr = *(const uint2*)&tg[i0*NF + 2*q];
        u32 x = xfb32[r*64 + q];
        float lo = us2f((u16)pr.x), hi = us2f((u16)(pr.x>>16));
        aa[j] += us2f((u16)x)      *(lo + (hi-lo)*fr);
        lo = us2f((u16)pr.y); hi = us2f((u16)(pr.y>>16));
        bb[j] += us2f((u16)(x>>16))*(lo + (hi-lo)*fr);
      }
    }
    for(; p < p1; p++){
      int r = row_s[p];
      float tf = wEs[p]*invD;
      int i0 = min((int)tf, TROWS-2);
      float fr = tf - (float)i0;
      uint2 pr = *(const uint2*)&tg[i0*NF + 2*q];
      u32 x = xfb32[r*64 + q];
      float lo = us2f((u16)pr.x), hi = us2f((u16)(pr.x>>16));
      aa[0] += us2f((u16)x)      *(lo + (hi-lo)*fr);
      lo = us2f((u16)pr.y); hi = us2f((u16)(pr.y>>16));
      bb[0] += us2f((u16)(x>>16))*(lo + (hi-lo)*fr);
    }
    float2 r2; r2.x = (aa[0]+aa[1])+(aa[2]+aa[3]); r2.y = (bb[0]+bb[1])+(bb[2]+bb[3]);
    *(float2*)&agg[n*NF + 2*q] = r2;
  } else {
    int bf = (l == NL-1) ? detect_bf(zraw) : 0;
    int lane = threadIdx.x & 63;
    int n = (b - NN/4)*4 + (threadIdx.x >> 6);
    const float* __restrict__ ts = tabS + l*TROWS;
    float cb = cbf[l] + d_r[n];
    int p0 = row_start[n], p1 = row_start[n+1];
    float px = pA[n*3+0], py = pA[n*3+1], pz = pA[n*3+2];
    float sx=0.f, sy=0.f, sz=0.f;
    for(int p = p0 + lane; p < p1; p += 64){
      int c = rcol_s[p];
      float tf = rw_s[p]*invD;
      int i0 = min((int)tf, TROWS-2);
      float fr = tf - (float)i0;
      float s0 = ts[i0], s1 = ts[i0+1];
      float acc = cb + d_c[c] + s0 + (s1-s0)*fr;
      sx += (px - pA[c*3+0])*acc;
      sy += (py - pA[c*3+1])*acc;
      sz += (pz - pA[c*3+2])*acc;
    }
    #pragma unroll
    for(int s=32; s>0; s>>=1){
      sx += __shfl_down(sx, s, 64);
      sy += __shfl_down(sy, s, 64);
      sz += __shfl_down(sz, s, 64);
    }
    if(lane == 0){
      int cnt = p1 - p0;
      float inv = (cnt > 0) ? 1.f/(float)cnt : 0.f;
      float ox = px + sx*inv, oy = py + sy*inv, oz = pz + sz*inv;
      if(l == NL-1){
        if(bf){
          u16* o = (u16*)out;
          o[n*3+0] = f2us(ox); o[n*3+1] = f2us(oy); o[n*3+2] = f2us(oz);
        } else {
          float* o = (float*)out;
          o[n*3+0] = ox; o[n*3+1] = oy; o[n*3+2] = oz;
        }
      } else {
        pB[n*3+0] = ox; pB[n*3+1] = oy; pB[n*3+2] = oz;
      }
    }
  }
}

// ---------- per-layer: fused h-update(l) + node(l+1) (xf + coord dots) ----------
__global__ void k_upnode(const float* __restrict__ agg, const float* __restrict__ l2t,
                         const float* __restrict__ l2bf, const float* __restrict__ lwt,
                         const float* __restrict__ lbf, int l, float* __restrict__ h,
                         const float* __restrict__ l1t, const float* __restrict__ cwf,
                         u16* __restrict__ xfb, float* __restrict__ d_r,
                         float* __restrict__ d_c, const u32* __restrict__ zraw,
                         void* __restrict__ out){
  __shared__ float sg[128][9];                    // ssp intermediate [k][node]
  __shared__ float hn[8][132];                    // h_new rows
  int t = threadIdx.x;                            // 256
  int f = t & 127, g = t >> 7;
  int n0 = blockIdx.x*8;                          // grid exact: NN/8
  int bf = (l == NL-1) ? detect_bf(zraw) : 0;
  // GEMV1: ssp(agg @ lin2^T + b)
  const float* __restrict__ wA = l2t + l*NF*HH;
  float bA = l2bf[l*HH + f];
  float acc[4];
  #pragma unroll
  for(int i=0;i<4;i++) acc[i] = bA;
  for(int k=0;k<NF;k++){
    float wv = wA[k*HH + f];
    #pragma unroll
    for(int i=0;i<4;i++) acc[i] += agg[(n0+g*4+i)*NF + k]*wv;   // uniform -> s_load
  }
  #pragma unroll
  for(int i=0;i<4;i++) sg[f][g*4+i] = sspf(acc[i]);
  __syncthreads();
  // GEMV2: h_new = h_old + sg @ lin^T + b
  const float* __restrict__ wB = lwt + l*HH*HH;
  float bB = lbf[l*HH + f];
  float acc2[4];
  #pragma unroll
  for(int i=0;i<4;i++) acc2[i] = bB;
  for(int k=0;k<HH;k++){
    float wv = wB[k*HH + f];
    #pragma unroll
    for(int i=0;i<4;i++) acc2[i] += sg[k][g*4+i]*wv;            // broadcast LDS
  }
  #pragma unroll
  for(int i=0;i<4;i++){
    int n = n0 + g*4 + i;
    float hv = h[n*HH + f] + acc2[i];
    if(l == NL-1){
      if(bf) ((u16*)out)[NN*3 + n*HH + f] = f2us(hv);
      else   ((float*)out)[NN*3 + n*HH + f] = hv;
    } else {
      h[n*HH + f] = hv;
      hn[g*4+i][f] = hv;
    }
  }
  if(l == NL-1) return;
  __syncthreads();
  // xf(l+1) = h_new @ lin1^T
  const float* __restrict__ wt = l1t + (l+1)*HH*NF;
  float acc3[4] = {0.f,0.f,0.f,0.f};
  for(int k=0;k<HH;k++){
    float wv = wt[k*NF + f];
    #pragma unroll
    for(int i=0;i<4;i++) acc3[i] += hn[g*4+i][k]*wv;            // broadcast LDS
  }
  #pragma unroll
  for(int i=0;i<4;i++) xfb[(n0+g*4+i)*NF + f] = f2us(acc3[i]);
  // coord dots(l+1): 32 lanes per node
  const float* __restrict__ cw = cwf + (l+1)*(GG + 2*HH);
  int j = t >> 5, lane32 = t & 31;
  float h0 = hn[j][lane32], h1 = hn[j][lane32+32];
  float h2 = hn[j][lane32+64], h3 = hn[j][lane32+96];
  float ar = h0*cw[GG+lane32]      + h1*cw[GG+lane32+32]
           + h2*cw[GG+lane32+64]   + h3*cw[GG+lane32+96];
  float ac = h0*cw[GG+HH+lane32]    + h1*cw[GG+HH+lane32+32]
           + h2*cw[GG+HH+lane32+64] + h3*cw[GG+HH+lane32+96];
  #pragma unroll
  for(int s=16; s>0; s>>=1){
    ar += __shfl_down(ar, s, 32);
    ac += __shfl_down(ac, s, 32);
  }
  if(lane32 == 0){ d_r[n0+j] = ar; d_c[n0+j] = ac; }
}

extern "C" void kernel_launch(void* const* d_in, const int* in_sizes, int n_in,
                              void* d_out, int out_size, void* d_ws, size_t ws_size,
                              hipStream_t stream){
  const u32*  z      = (const u32*)d_in[0];
  const void* pos_in = d_in[1];
  const int*  ei_raw = (const int*)d_in[2];
  const void* mlp1_w = d_in[3];
  const void* mlp1_b = d_in[4];
  const void* mlp2_w = d_in[5];
  const void* mlp2_b = d_in[6];
  const void* lin1_w = d_in[7];
  const void* lin2_w = d_in[8];
  const void* lin2_b = d_in[9];
  const void* lin_w  = d_in[10];
  const void* lin_b  = d_in[11];
  const void* coord_w= d_in[12];
  const void* coord_b= d_in[13];

  float* W = (float*)d_ws;
  float* h    = W; W += NN*HH;
  float* agg  = W; W += NN*NF;
  float* posA = W; W += NN*3;
  float* posB = W; W += NN*3;
  float* d_r  = W; W += NN;
  float* d_c  = W; W += NN;
  float* wE   = W; W += EE;
  float* wEs  = W; W += EE;
  float* rw_s = W; W += EE;
  float* b1f  = W; W += NL*NF;
  float* b2v  = W; W += NL*NF;
  float* w1t  = W; W += NL*GG*NF;
  float* w2t  = W; W += NL*NF*NF;
  float* l1t  = W; W += NL*NF*HH;
  float* l2t  = W; W += NL*HH*NF;
  float* l2bf = W; W += NL*HH;
  float* lwt  = W; W += NL*HH*HH;
  float* lbf  = W; W += NL*HH;
  float* cwf  = W; W += NL*(GG+2*HH);
  float* cbf  = W; W += NL;
  W = (float*)(((uintptr_t)W + 63) & ~(uintptr_t)63);
  u32*  tabGb = (u32*)W; W += (size_t)NL*TROWS*NF;
  float* tabS = W; W += NL*TROWS;
  u16* xfb = (u16*)W; W += (NN*NF)/2;
  u32* partR = (u32*)W; W += (size_t)NB*NN;
  u32* partC = (u32*)W; W += (size_t)NB*NN;
  int* degR      = (int*)W; W += NN;
  int* degC      = (int*)W; W += NN;
  int* col_start = (int*)W; W += NN+1;
  int* row_start = (int*)W; W += NN+1;
  int* row_s     = (int*)W; W += EE;
  int* rcol_s    = (int*)W; W += EE;
  int* eiN       = (int*)W; W += 2*EE;
  int* wmaxi     = (int*)W; W += 1;

  k_prep<<<NN*HH/256 + NL*NF*NF/256, 256, 0, stream>>>(
      z, pos_in, mlp1_w, mlp1_b, mlp2_w, mlp2_b, lin1_w, lin2_w, lin2_b,
      lin_w, lin_b, coord_w, coord_b,
      h, posA, wmaxi,
      b1f, b2v, w1t, w2t, l1t, l2t, l2bf, lwt, lbf, cwf, cbf);
  k_count<<<NB, 256, 0, stream>>>(ei_raw, posA, eiN, wE, partR, partC, wmaxi);
  k_sumpref<<<(NN+255)/256, 256, 0, stream>>>(partR, partC, degR, degC);
  k_scan2<<<1, 1024, 0, stream>>>(degC, degR, col_start, row_start);
  k_setup2<<<NB + NL*128 + NN/8 + NN/4, 256, 0, stream>>>(
      eiN, wE, col_start, row_start, partR, partC,
      row_s, wEs, rcol_s, rw_s,
      w1t, b1f, w2t, b2v, cwf, wmaxi, tabGb, tabS,
      h, l1t, xfb, d_r, d_c);

  float* pA = posA;
  float* pB = posB;
  for(int l=0; l<NL; l++){
    k_agg<<<NN/4 + NN/4, 256, 0, stream>>>(col_start, row_s, wEs, (const u32*)xfb,
                                           tabGb, wmaxi, l, agg,
                                           row_start, rcol_s, rw_s, d_r, d_c,
                                           tabS, cbf, pA, pB, z, d_out);
    k_upnode<<<NN/8, 256, 0, stream>>>(agg, l2t, l2bf, lwt, lbf, l, h,
                                       l1t, cwf, xfb, d_r, d_c, z, d_out);
    float* tmp = pA; pA = pB; pB = tmp;
  }
}

// Round 11
// 433.544 us; speedup vs baseline: 1.9126x; 1.3374x over previous
//
#include <hip/hip_runtime.h>

// SchNet on MI355X — round 11: k_setup2 split (LDS-occupancy), MFMA k_upnode
// (16 nodes/block, bf16 weights row-major), u16 partial histograms.
// Table-based edge MLP + atomic-free CSR + fused layer loop retained.

#define NN 10000
#define EE 320000
#define HH 128
#define GG 50
#define NF 128
#define NL 6
#define TROWS 2048
#define NB 128          // histogram blocks; EE/NB = 2500 edges each (fits u16)

typedef unsigned short u16;
typedef unsigned int u32;
typedef short bf16x8 __attribute__((ext_vector_type(8)));
typedef float f32x4  __attribute__((ext_vector_type(4)));

__device__ __forceinline__ float us2f(u16 u){
  union { float f; u32 i; } v; v.i = ((u32)u) << 16; return v.f;
}
__device__ __forceinline__ u16 f2us(float x){
  union { float f; u32 i; } v; v.f = x;
  u32 r = v.i + 0x7fffu + ((v.i >> 16) & 1u);   // RNE
  return (u16)(r >> 16);
}
__device__ __forceinline__ float ldin(const void* p, int i, int bf){
  return bf ? us2f(((const u16*)p)[i]) : ((const float*)p)[i];
}
__device__ __forceinline__ float sspf(float x){
  return fmaxf(x, 0.f) + __logf(1.f + __expf(-fabsf(x))) - 0.6931472f;
}
// deterministic inline dtype probes (same 256 words for every wave)
__device__ __forceinline__ int detect_bf(const u32* __restrict__ zraw){
  int lane = threadIdx.x & 63;
  int c = 0;
  #pragma unroll
  for(int j=0;j<4;j++){
    u32 w = zraw[lane*4+j];
    u32 hb = (w >> 8) & 0x7F;
    c += (hb >= 0x38 && hb <= 0x41) ? 1 : 0;
  }
  return __popcll(__ballot(c >= 2)) >= 32;
}
__device__ __forceinline__ int detect_i64(const int* __restrict__ ei_raw){
  int lane = threadIdx.x & 63;
  int c = 0;
  #pragma unroll
  for(int j=0;j<4;j++) c += (ei_raw[2*(lane*4+j)+1] == 0) ? 1 : 0;
  return __popcll(__ballot(c >= 3)) >= 32;
}

// ---------- K1: fused init + weight prep ----------
__global__ void k_prep(const u32* __restrict__ zraw, const void* __restrict__ pos_in,
    const void* __restrict__ mlp1_w, const void* __restrict__ mlp1_b,
    const void* __restrict__ mlp2_w, const void* __restrict__ mlp2_b,
    const void* __restrict__ lin1_w, const void* __restrict__ lin2_w,
    const void* __restrict__ lin2_b, const void* __restrict__ lin_w,
    const void* __restrict__ lin_b,  const void* __restrict__ coord_w,
    const void* __restrict__ coord_b,
    float* __restrict__ h, float* __restrict__ pos, int* __restrict__ wmaxi,
    float* __restrict__ b1f, float* __restrict__ b2v,
    float* __restrict__ w1t, float* __restrict__ w2t,
    float* __restrict__ l1t, u16* __restrict__ l1b, u16* __restrict__ l2b,
    float* __restrict__ l2bf, u16* __restrict__ lwb,
    float* __restrict__ lbf, float* __restrict__ cwf, float* __restrict__ cbf)
{
  int bf = detect_bf(zraw);
  int b = blockIdx.x;
  if(b < NN*HH/256){
    int i = b*256 + threadIdx.x;
    h[i] = ldin(zraw, i, bf);
    if(i < NN*3) pos[i] = ldin(pos_in, i, bf);
    if(i == 0) *wmaxi = 0;
  } else {
    int i = (b - NN*HH/256)*256 + threadIdx.x;    // < NL*NF*NF
    if(i < NL*NF){
      b1f[i]  = ldin(mlp1_b, i, bf);
      b2v[i]  = ldin(mlp2_b, i, bf);
      l2bf[i] = ldin(lin2_b, i, bf);
      lbf[i]  = ldin(lin_b,  i, bf);
    }
    if(i < NL*GG*NF){                             // w1t[l][g][f]
      int l = i/(GG*NF), rem = i%(GG*NF);
      int g = rem/NF, f = rem%NF;
      w1t[i] = ldin(mlp1_w, (l*NF + f)*GG + g, bf);
    }
    if(i < NL*NF*NF){
      int l = i/(NF*NF), rem = i%(NF*NF);
      int k = rem/NF, f = rem%NF;
      w2t[i] = ldin(mlp2_w, l*NF*NF + f*NF + k, bf);
      l1t[i] = ldin(lin1_w, l*NF*HH + f*HH + k, bf);
      l1b[i] = f2us(ldin(lin1_w, i, bf));         // row-major bf16 (MFMA B)
      l2b[i] = f2us(ldin(lin2_w, i, bf));
      lwb[i] = f2us(ldin(lin_w,  i, bf));
    }
    if(i < NL*(GG+2*HH)) cwf[i] = ldin(coord_w, i, bf);
    if(i < NL) cbf[i] = ldin(coord_b, i, bf);
  }
}

// ---------- K2: decode ei, distances, LDS histograms -> u16 partials ----------
__global__ void k_count(const int* __restrict__ ei_raw, const float* __restrict__ pos,
                        int* __restrict__ eiN, float* __restrict__ wE,
                        u32* __restrict__ partR32, u32* __restrict__ partC32,
                        int* __restrict__ wmaxi){
  __shared__ u32 hr[NN/2];
  __shared__ u32 hc[NN/2];
  int is64 = detect_i64(ei_raw);
  int b = blockIdx.x, tid = threadIdx.x;          // grid: NB x 256
  for(int i=tid; i<NN/2; i+=256){ hr[i]=0; hc[i]=0; }
  __syncthreads();
  int e0 = b*(EE/NB), e1 = e0 + EE/NB;
  float wm = 0.f;
  for(int e = e0 + tid; e < e1; e += 256){
    int r = is64 ? ei_raw[2*e] : ei_raw[e];
    int c = is64 ? ei_raw[2*(EE+e)] : ei_raw[EE+e];
    eiN[e] = r; eiN[EE+e] = c;
    float dx = pos[r*3+0]-pos[c*3+0];
    float dy = pos[r*3+1]-pos[c*3+1];
    float dz = pos[r*3+2]-pos[c*3+2];
    float w = sqrtf(dx*dx + dy*dy + dz*dz);
    wE[e] = w;
    wm = fmaxf(wm, w);
    atomicAdd(&hr[r>>1], (r&1) ? 0x10000u : 1u);
    atomicAdd(&hc[c>>1], (c&1) ? 0x10000u : 1u);
  }
  #pragma unroll
  for(int s=32; s>0; s>>=1) wm = fmaxf(wm, __shfl_down(wm, s, 64));
  if((tid & 63) == 0) atomicMax(wmaxi, __float_as_int(wm));
  __syncthreads();
  // u32 = two packed u16 node counts (little-endian n=2i low, 2i+1 high)
  for(int i=tid; i<NN/2; i+=256){
    partR32[(size_t)b*(NN/2) + i] = hr[i];
    partC32[(size_t)b*(NN/2) + i] = hc[i];
  }
}

// ---------- K3: u16 partials -> exclusive block-prefixes + totals ----------
__global__ void k_sumpref(u16* __restrict__ partR16, u16* __restrict__ partC16,
                          int* __restrict__ degR, int* __restrict__ degC){
  int n = blockIdx.x*256 + threadIdx.x;
  if(n >= NN) return;
  u32 rr = 0, rc = 0;
  for(int b=0; b<NB; b++){
    u32 vr = partR16[(size_t)b*NN + n], vc = partC16[(size_t)b*NN + n];
    partR16[(size_t)b*NN + n] = (u16)rr;
    partC16[(size_t)b*NN + n] = (u16)rc;
    rr += vr; rc += vc;
  }
  degR[n] = (int)rr; degC[n] = (int)rc;
}

// ---------- K4: fused dual exclusive scan ----------
__global__ void k_scan2(const int* __restrict__ col_deg, const int* __restrict__ deg_row,
                        int* __restrict__ col_start, int* __restrict__ row_start){
  __shared__ int part[1024];
  int tid = threadIdx.x;
  const int CH = (NN + 1023)/1024;
  for(int pass=0; pass<2; pass++){
    const int* deg = pass ? deg_row : col_deg;
    int* start = pass ? row_start : col_start;
    int base = tid*CH;
    int s = 0;
    for(int i=0;i<CH;i++){ int idx=base+i; if(idx<NN) s += deg[idx]; }
    part[tid] = s;
    __syncthreads();
    for(int off=1; off<1024; off<<=1){
      int v = (tid>=off) ? part[tid-off] : 0;
      __syncthreads();
      part[tid] += v;
      __syncthreads();
    }
    int run = (tid==0) ? 0 : part[tid-1];
    for(int i=0;i<CH;i++){
      int idx = base+i;
      if(idx<NN){ start[idx]=run; run += deg[idx]; }
    }
    if(tid==1023) start[NN] = run;
    __syncthreads();
  }
}

// ---------- K5a: CSR fill via LDS rank histograms (40 KB LDS, NB blocks) ----------
__global__ void k_fill(const int* __restrict__ eiN, const float* __restrict__ wE,
                       const int* __restrict__ col_start, const int* __restrict__ row_start,
                       const u16* __restrict__ partR16, const u16* __restrict__ partC16,
                       int* __restrict__ row_s, float* __restrict__ wEs,
                       int* __restrict__ rcol_s, float* __restrict__ rw_s){
  __shared__ u32 hr[NN/2];
  __shared__ u32 hc[NN/2];
  int b = blockIdx.x, t = threadIdx.x;
  for(int i=t; i<NN/2; i+=256){ hr[i]=0; hc[i]=0; }
  __syncthreads();
  int e0 = b*(EE/NB), e1 = e0 + EE/NB;
  for(int e = e0 + t; e < e1; e += 256){
    int r = eiN[e], c = eiN[EE+e];
    float w = wE[e];
    u32 oldc = atomicAdd(&hc[c>>1], (c&1) ? 0x10000u : 1u);
    u32 rkc = (c&1) ? (oldc >> 16) : (oldc & 0xFFFFu);
    int p = col_start[c] + (int)partC16[(size_t)b*NN + c] + (int)rkc;
    row_s[p] = r; wEs[p] = w;
    u32 oldr = atomicAdd(&hr[r>>1], (r&1) ? 0x10000u : 1u);
    u32 rkr = (r&1) ? (oldr >> 16) : (oldr & 0xFFFFu);
    int p2 = row_start[r] + (int)partR16[(size_t)b*NN + r] + (int)rkr;
    rcol_s[p2] = c; rw_s[p2] = w;
  }
}

// ---------- K5b: table build+pack (blocks 0..NL*128-1) + layer-0 node (rest) ----------
__global__ void k_tabnode(const float* __restrict__ w1t, const float* __restrict__ b1f,
                          const float* __restrict__ w2t, const float* __restrict__ b2v,
                          const float* __restrict__ cwf, const int* __restrict__ wmaxi,
                          u32* __restrict__ tabGb, float* __restrict__ tabS,
                          const float* __restrict__ h, const float* __restrict__ l1t,
                          u16* __restrict__ xfb, float* __restrict__ d_r,
                          float* __restrict__ d_c){
  __shared__ float attr[17*64];                   // 4.25 KB
  __shared__ float tls[128*19];                   // 9.5 KB
  int b = blockIdx.x, t = threadIdx.x;
  if(b < NL*128){
    int l = b >> 7;
    int r0 = (b & 127)*16;
    int f = t & 127, half = t >> 7;
    float delta = __int_as_float(*wmaxi) / (float)(TROWS-1);
    for(int idx=t; idx<17*64; idx+=256){
      int r = idx >> 6, g = idx & 63;
      int row = min(r0 + r, TROWS-1);
      float w = (float)row*delta;
      float d = w - (float)g*(10.f/49.f);
      attr[idx] = (g < GG) ? __expf(-12.005f*d*d) : 0.f;
    }
    __syncthreads();
    const float* __restrict__ w1 = w1t + l*GG*NF;
    float b1 = b1f[l*NF + f];
    float a1[9];
    #pragma unroll
    for(int r=0;r<9;r++) a1[r] = b1;
    for(int g=0; g<GG; g++){
      float wv = w1[g*NF + f];
      #pragma unroll
      for(int r=0;r<9;r++) a1[r] += attr[(half*8 + r)*64 + g]*wv;
    }
    #pragma unroll
    for(int r=0;r<9;r++) tls[f*19 + half*9 + r] = sspf(a1[r]);
    __syncthreads();
    const float* __restrict__ w2 = w2t + l*NF*NF;
    float b2 = b2v[l*NF + f];
    float a2[9];
    #pragma unroll
    for(int r=0;r<9;r++) a2[r] = b2;
    for(int k=0;k<NF;k++){
      float wv = w2[k*NF + f];
      #pragma unroll
      for(int r=0;r<9;r++) a2[r] += tls[k*19 + half*9 + r]*wv;
    }
    float v[9];
    #pragma unroll
    for(int r=0;r<9;r++){
      int row = min(r0 + half*8 + r, TROWS-1);
      float w = (float)row*delta;
      float C = 0.5f*(cosf(w*0.3141592653589793f) + 1.f);
      v[r] = a2[r]*C;
    }
    #pragma unroll
    for(int j=0;j<8;j++){
      int row = r0 + half*8 + j;
      tabGb[((size_t)l*TROWS + row)*NF + f] = (u32)f2us(v[j]) | ((u32)f2us(v[j+1]) << 16);
    }
    if(t < 16){
      const float* __restrict__ cwg = cwf + l*(GG+2*HH);
      float s = 0.f;
      for(int g=0; g<GG; g++) s += attr[t*64 + g]*cwg[g];
      tabS[l*TROWS + r0 + t] = s;
    }
  } else {
    int nb = b - NL*128;
    if(nb < NN/8){
      int f = t & 127, g = t >> 7;
      int n0 = nb*8 + g*4;
      const float* __restrict__ wt = l1t;         // l=0 [k][f]
      float acc[4] = {0.f,0.f,0.f,0.f};
      for(int k=0;k<HH;k++){
        float wv = wt[k*NF + f];
        #pragma unroll
        for(int i=0;i<4;i++) acc[i] += h[(n0+i)*HH + k]*wv;
      }
      #pragma unroll
      for(int i=0;i<4;i++) xfb[(n0+i)*NF + f] = f2us(acc[i]);
    } else {
      int lane = t & 63;
      int n = (nb - NN/8)*4 + (t >> 6);
      const float* __restrict__ cw = cwf;         // l=0
      float h0 = h[n*HH + lane], h1 = h[n*HH + 64 + lane];
      float ar = h0*cw[GG + lane]      + h1*cw[GG + 64 + lane];
      float ac = h0*cw[GG + HH + lane] + h1*cw[GG + HH + 64 + lane];
      #pragma unroll
      for(int s=32; s>0; s>>=1){
        ar += __shfl_down(ar, s, 64);
        ac += __shfl_down(ac, s, 64);
      }
      if(lane == 0){ d_r[n] = ar; d_c[n] = ac; }
    }
  }
}

// ---------- per-layer: fused aggregation (cfagg + coordagg) ----------
__global__ void k_agg(const int* __restrict__ col_start, const int* __restrict__ row_s,
                      const float* __restrict__ wEs, const u32* __restrict__ xfb32,
                      const u32* __restrict__ tabGb, const int* __restrict__ wmaxi,
                      int l, float* __restrict__ agg,
                      const int* __restrict__ row_start, const int* __restrict__ rcol_s,
                      const float* __restrict__ rw_s, const float* __restrict__ d_r,
                      const float* __restrict__ d_c, const float* __restrict__ tabS,
                      const float* __restrict__ cbf,
                      const float* __restrict__ pA, float* __restrict__ pB,
                      const u32* __restrict__ zraw, void* __restrict__ out){
  int b = blockIdx.x;                             // grid: NN/4 + NN/4
  float invD = (float)(TROWS-1) / __int_as_float(*wmaxi);
  if(b < NN/4){
    int n = b*4 + (threadIdx.x >> 6);
    int q = threadIdx.x & 63;
    const u32* __restrict__ tg = tabGb + (size_t)l*TROWS*NF;
    int p0 = col_start[n], p1 = col_start[n+1];
    float aa[4] = {0.f,0.f,0.f,0.f};
    float bb[4] = {0.f,0.f,0.f,0.f};
    int p = p0;
    for(; p+4 <= p1; p += 4){
      #pragma unroll
      for(int j=0;j<4;j++){
        int r = row_s[p+j];
        float tf = wEs[p+j]*invD;
        int i0 = min((int)tf, TROWS-2);
        float fr = tf - (float)i0;
        uint2 pr = *(const uint2*)&tg[i0*NF + 2*q];
        u32 x = xfb32[r*64 + q];
        float lo = us2f((u16)pr.x), hi = us2f((u16)(pr.x>>16));
        aa[j] += us2f((u16)x)      *(lo + (hi-lo)*fr);
        lo = us2f((u16)pr.y); hi = us2f((u16)(pr.y>>16));
        bb[j] += us2f((u16)(x>>16))*(lo + (hi-lo)*fr);
      }
    }
    for(; p < p1; p++){
      int r = row_s[p];
      float tf = wEs[p]*invD;
      int i0 = min((int)tf, TROWS-2);
      float fr = tf - (float)i0;
      uint2 pr = *(const uint2*)&tg[i0*NF + 2*q];
      u32 x = xfb32[r*64 + q];
      float lo = us2f((u16)pr.x), hi = us2f((u16)(pr.x>>16));
      aa[0] += us2f((u16)x)      *(lo + (hi-lo)*fr);
      lo = us2f((u16)pr.y); hi = us2f((u16)(pr.y>>16));
      bb[0] += us2f((u16)(x>>16))*(lo + (hi-lo)*fr);
    }
    float2 r2; r2.x = (aa[0]+aa[1])+(aa[2]+aa[3]); r2.y = (bb[0]+bb[1])+(bb[2]+bb[3]);
    *(float2*)&agg[n*NF + 2*q] = r2;
  } else {
    int bf = (l == NL-1) ? detect_bf(zraw) : 0;
    int lane = threadIdx.x & 63;
    int n = (b - NN/4)*4 + (threadIdx.x >> 6);
    const float* __restrict__ ts = tabS + l*TROWS;
    float cb = cbf[l] + d_r[n];
    int p0 = row_start[n], p1 = row_start[n+1];
    float px = pA[n*3+0], py = pA[n*3+1], pz = pA[n*3+2];
    float sx=0.f, sy=0.f, sz=0.f;
    for(int p = p0 + lane; p < p1; p += 64){
      int c = rcol_s[p];
      float tf = rw_s[p]*invD;
      int i0 = min((int)tf, TROWS-2);
      float fr = tf - (float)i0;
      float s0 = ts[i0], s1 = ts[i0+1];
      float acc = cb + d_c[c] + s0 + (s1-s0)*fr;
      sx += (px - pA[c*3+0])*acc;
      sy += (py - pA[c*3+1])*acc;
      sz += (pz - pA[c*3+2])*acc;
    }
    #pragma unroll
    for(int s=32; s>0; s>>=1){
      sx += __shfl_down(sx, s, 64);
      sy += __shfl_down(sy, s, 64);
      sz += __shfl_down(sz, s, 64);
    }
    if(lane == 0){
      int cnt = p1 - p0;
      float inv = (cnt > 0) ? 1.f/(float)cnt : 0.f;
      float ox = px + sx*inv, oy = py + sy*inv, oz = pz + sz*inv;
      if(l == NL-1){
        if(bf){
          u16* o = (u16*)out;
          o[n*3+0] = f2us(ox); o[n*3+1] = f2us(oy); o[n*3+2] = f2us(oz);
        } else {
          float* o = (float*)out;
          o[n*3+0] = ox; o[n*3+1] = oy; o[n*3+2] = oz;
        }
      } else {
        pB[n*3+0] = ox; pB[n*3+1] = oy; pB[n*3+2] = oz;
      }
    }
  }
}

// ---------- per-layer: MFMA h-update(l) + node(l+1). 16 nodes/block, 4 waves.
// Frag layouts (round-3 validated): A[m=lane&15][k=quad*8+j] (LDS stride 136),
// B[n=lane&15][k] (row-major bf16 global), C: col=lane&15, row=quad*4+reg.
__global__ void k_upnode(const float* __restrict__ agg, const u16* __restrict__ l2b,
                         const float* __restrict__ l2bf, const u16* __restrict__ lwb,
                         const float* __restrict__ lbf, int l, float* __restrict__ h,
                         const u16* __restrict__ l1b, const float* __restrict__ cwf,
                         u16* __restrict__ xfb, float* __restrict__ d_r,
                         float* __restrict__ d_c, const u32* __restrict__ zraw,
                         void* __restrict__ out){
  __shared__ __align__(16) u16 T[16*136];         // 4.25 KB
  int t = threadIdx.x;
  int lane = t & 63;
  int m16 = lane & 15;
  int quad = lane >> 4;
  int wave = t >> 6;
  int n0 = blockIdx.x*16;                         // grid exact: NN/16
  int bf = (l == NL-1) ? detect_bf(zraw) : 0;

  // A-frags of agg (identical across waves)
  bf16x8 aA[4];
  {
    const float* __restrict__ src = &agg[(n0+m16)*NF];
    #pragma unroll
    for(int ks=0; ks<4; ks++){
      float4 u0 = *(const float4*)&src[ks*32 + quad*8];
      float4 u1 = *(const float4*)&src[ks*32 + quad*8 + 4];
      aA[ks][0]=(short)f2us(u0.x); aA[ks][1]=(short)f2us(u0.y);
      aA[ks][2]=(short)f2us(u0.z); aA[ks][3]=(short)f2us(u0.w);
      aA[ks][4]=(short)f2us(u1.x); aA[ks][5]=(short)f2us(u1.y);
      aA[ks][6]=(short)f2us(u1.z); aA[ks][7]=(short)f2us(u1.w);
    }
  }
  // GEMM1: sg = ssp(agg @ lin2^T + b); 2 N-tiles/wave
  f32x4 acc[2];
  {
    const u16* __restrict__ wA = l2b + l*HH*NF;
    #pragma unroll
    for(int x=0;x<2;x++){
      float bv = l2bf[l*HH + (wave*2+x)*16 + m16];
      acc[x] = (f32x4){bv,bv,bv,bv};
    }
    #pragma unroll
    for(int ks=0; ks<4; ks++)
      #pragma unroll
      for(int x=0;x<2;x++){
        bf16x8 bb = *(const bf16x8*)&wA[((wave*2+x)*16 + m16)*NF + ks*32 + quad*8];
        acc[x] = __builtin_amdgcn_mfma_f32_16x16x32_bf16(aA[ks], bb, acc[x], 0,0,0);
      }
    #pragma unroll
    for(int x=0;x<2;x++)
      #pragma unroll
      for(int r=0;r<4;r++)
        T[(quad*4+r)*136 + (wave*2+x)*16 + m16] = f2us(sspf(acc[x][r]));
  }
  __syncthreads();
  // GEMM2: hv = h + sg @ lin^T + b
  float hv[2][4];
  {
    bf16x8 aS[4];
    #pragma unroll
    for(int ks=0; ks<4; ks++)
      aS[ks] = *(const bf16x8*)&T[m16*136 + ks*32 + quad*8];
    const u16* __restrict__ wB = lwb + l*HH*HH;
    #pragma unroll
    for(int x=0;x<2;x++){
      float bv = lbf[l*HH + (wave*2+x)*16 + m16];
      acc[x] = (f32x4){bv,bv,bv,bv};
    }
    #pragma unroll
    for(int ks=0; ks<4; ks++)
      #pragma unroll
      for(int x=0;x<2;x++){
        bf16x8 bb = *(const bf16x8*)&wB[((wave*2+x)*16 + m16)*HH + ks*32 + quad*8];
        acc[x] = __builtin_amdgcn_mfma_f32_16x16x32_bf16(aS[ks], bb, acc[x], 0,0,0);
      }
    #pragma unroll
    for(int x=0;x<2;x++)
      #pragma unroll
      for(int r=0;r<4;r++){
        int n = n0 + quad*4 + r;
        hv[x][r] = h[n*HH + (wave*2+x)*16 + m16] + acc[x][r];
      }
  }
  if(l == NL-1){
    #pragma unroll
    for(int x=0;x<2;x++)
      #pragma unroll
      for(int r=0;r<4;r++){
        int n = n0 + quad*4 + r;
        int f = (wave*2+x)*16 + m16;
        if(bf) ((u16*)out)[NN*3 + n*HH + f] = f2us(hv[x][r]);
        else   ((float*)out)[NN*3 + n*HH + f] = hv[x][r];
      }
    return;
  }
  __syncthreads();                                // all waves done reading T(sg)
  #pragma unroll
  for(int x=0;x<2;x++)
    #pragma unroll
    for(int r=0;r<4;r++){
      int n = n0 + quad*4 + r;
      int f = (wave*2+x)*16 + m16;
      h[n*HH + f] = hv[x][r];
      T[(quad*4+r)*136 + f] = f2us(hv[x][r]);     // hn for xf + dots
    }
  __syncthreads();
  // GEMM3: xf(l+1) = h_new @ lin1^T
  {
    bf16x8 aH[4];
    #pragma unroll
    for(int ks=0; ks<4; ks++)
      aH[ks] = *(const bf16x8*)&T[m16*136 + ks*32 + quad*8];
    const u16* __restrict__ wC = l1b + (l+1)*NF*HH;
    #pragma unroll
    for(int x=0;x<2;x++) acc[x] = (f32x4){0.f,0.f,0.f,0.f};
    #pragma unroll
    for(int ks=0; ks<4; ks++)
      #pragma unroll
      for(int x=0;x<2;x++){
        bf16x8 bb = *(const bf16x8*)&wC[((wave*2+x)*16 + m16)*HH + ks*32 + quad*8];
        acc[x] = __builtin_amdgcn_mfma_f32_16x16x32_bf16(aH[ks], bb, acc[x], 0,0,0);
      }
    #pragma unroll
    for(int x=0;x<2;x++)
      #pragma unroll
      for(int r=0;r<4;r++)
        xfb[(n0+quad*4+r)*NF + (wave*2+x)*16 + m16] = f2us(acc[x][r]);
  }
  // coord dots(l+1) from hn (16 threads/node)
  {
    const float* __restrict__ cw = cwf + (l+1)*(GG + 2*HH);
    int j = t >> 4, l16 = t & 15;
    float ar = 0.f, ac = 0.f;
    #pragma unroll
    for(int i=0;i<8;i++){
      float hvv = us2f(T[j*136 + l16 + 16*i]);
      ar += hvv*cw[GG + l16 + 16*i];
      ac += hvv*cw[GG + HH + l16 + 16*i];
    }
    #pragma unroll
    for(int s=8; s>0; s>>=1){
      ar += __shfl_down(ar, s, 16);
      ac += __shfl_down(ac, s, 16);
    }
    if(l16 == 0){ d_r[n0+j] = ar; d_c[n0+j] = ac; }
  }
}

extern "C" void kernel_launch(void* const* d_in, const int* in_sizes, int n_in,
                              void* d_out, int out_size, void* d_ws, size_t ws_size,
                              hipStream_t stream){
  const u32*  z      = (const u32*)d_in[0];
  const void* pos_in = d_in[1];
  const int*  ei_raw = (const int*)d_in[2];
  const void* mlp1_w = d_in[3];
  const void* mlp1_b = d_in[4];
  const void* mlp2_w = d_in[5];
  const void* mlp2_b = d_in[6];
  const void* lin1_w = d_in[7];
  const void* lin2_w = d_in[8];
  const void* lin2_b = d_in[9];
  const void* lin_w  = d_in[10];
  const void* lin_b  = d_in[11];
  const void* coord_w= d_in[12];
  const void* coord_b= d_in[13];

  float* W = (float*)d_ws;
  float* h    = W; W += NN*HH;
  float* agg  = W; W += NN*NF;
  float* posA = W; W += NN*3;
  float* posB = W; W += NN*3;
  float* d_r  = W; W += NN;
  float* d_c  = W; W += NN;
  float* wE   = W; W += EE;
  float* wEs  = W; W += EE;
  float* rw_s = W; W += EE;
  float* b1f  = W; W += NL*NF;
  float* b2v  = W; W += NL*NF;
  float* w1t  = W; W += NL*GG*NF;
  float* w2t  = W; W += NL*NF*NF;
  float* l1t  = W; W += NL*NF*HH;
  float* l2bf = W; W += NL*HH;
  float* lbf  = W; W += NL*HH;
  float* cwf  = W; W += NL*(GG+2*HH);
  float* cbf  = W; W += NL;
  W = (float*)(((uintptr_t)W + 63) & ~(uintptr_t)63);
  u32*  tabGb = (u32*)W; W += (size_t)NL*TROWS*NF;
  float* tabS = W; W += NL*TROWS;
  u16* l1b = (u16*)W; W += (NL*NF*NF)/2;
  u16* l2b = (u16*)W; W += (NL*NF*NF)/2;
  u16* lwb = (u16*)W; W += (NL*NF*NF)/2;
  u16* xfb = (u16*)W; W += (NN*NF)/2;
  u16* partR16 = (u16*)W; W += (size_t)NB*NN/2;   // 2.56 MB
  u16* partC16 = (u16*)W; W += (size_t)NB*NN/2;
  int* degR      = (int*)W; W += NN;
  int* degC      = (int*)W; W += NN;
  int* col_start = (int*)W; W += NN+1;
  int* row_start = (int*)W; W += NN+1;
  int* row_s     = (int*)W; W += EE;
  int* rcol_s    = (int*)W; W += EE;
  int* eiN       = (int*)W; W += 2*EE;
  int* wmaxi     = (int*)W; W += 1;

  k_prep<<<NN*HH/256 + NL*NF*NF/256, 256, 0, stream>>>(
      z, pos_in, mlp1_w, mlp1_b, mlp2_w, mlp2_b, lin1_w, lin2_w, lin2_b,
      lin_w, lin_b, coord_w, coord_b,
      h, posA, wmaxi,
      b1f, b2v, w1t, w2t, l1t, l1b, l2b, l2bf, lwb, lbf, cwf, cbf);
  k_count<<<NB, 256, 0, stream>>>(ei_raw, posA, eiN, wE,
                                  (u32*)partR16, (u32*)partC16, wmaxi);
  k_sumpref<<<(NN+255)/256, 256, 0, stream>>>(partR16, partC16, degR, degC);
  k_scan2<<<1, 1024, 0, stream>>>(degC, degR, col_start, row_start);
  k_fill<<<NB, 256, 0, stream>>>(eiN, wE, col_start, row_start, partR16, partC16,
                                 row_s, wEs, rcol_s, rw_s);
  k_tabnode<<<NL*128 + NN/8 + NN/4, 256, 0, stream>>>(
      w1t, b1f, w2t, b2v, cwf, wmaxi, tabGb, tabS,
      h, l1t, xfb, d_r, d_c);

  float* pA = posA;
  float* pB = posB;
  for(int l=0; l<NL; l++){
    k_agg<<<NN/4 + NN/4, 256, 0, stream>>>(col_start, row_s, wEs, (const u32*)xfb,
                                           tabGb, wmaxi, l, agg,
                                           row_start, rcol_s, rw_s, d_r, d_c,
                                           tabS, cbf, pA, pB, z, d_out);
    k_upnode<<<NN/16, 256, 0, stream>>>(agg, l2b, l2bf, lwb, lbf, l, h,
                                        l1b, cwf, xfb, d_r, d_c, z, d_out);
    float* tmp = pA; pA = pB; pB = tmp;
  }
}

// Round 12
// 414.217 us; speedup vs baseline: 2.0019x; 1.0467x over previous
//
#include <hip/hip_runtime.h>

// SchNet on MI355X — round 12: per-layer fusion (k_agg + k_upnode -> k_layer,
// 512 thr: 8-wave CSR gather straight into LDS A-frags, then MFMA GEMM1/2/3 +
// dots + xfb; coordagg as tail blocks). 18 -> 12 dispatches, no agg global
// round-trip. Table-based edge MLP + atomic-free CSR retained.

#define NN 10000
#define EE 320000
#define HH 128
#define GG 50
#define NF 128
#define NL 6
#define TROWS 2048
#define NB 128          // histogram blocks; EE/NB = 2500 edges each (fits u16)

typedef unsigned short u16;
typedef unsigned int u32;
typedef short bf16x8 __attribute__((ext_vector_type(8)));
typedef float f32x4  __attribute__((ext_vector_type(4)));

__device__ __forceinline__ float us2f(u16 u){
  union { float f; u32 i; } v; v.i = ((u32)u) << 16; return v.f;
}
__device__ __forceinline__ u16 f2us(float x){
  union { float f; u32 i; } v; v.f = x;
  u32 r = v.i + 0x7fffu + ((v.i >> 16) & 1u);   // RNE
  return (u16)(r >> 16);
}
__device__ __forceinline__ float ldin(const void* p, int i, int bf){
  return bf ? us2f(((const u16*)p)[i]) : ((const float*)p)[i];
}
__device__ __forceinline__ float sspf(float x){
  return fmaxf(x, 0.f) + __logf(1.f + __expf(-fabsf(x))) - 0.6931472f;
}
// deterministic inline dtype probes (same 256 words for every wave)
__device__ __forceinline__ int detect_bf(const u32* __restrict__ zraw){
  int lane = threadIdx.x & 63;
  int c = 0;
  #pragma unroll
  for(int j=0;j<4;j++){
    u32 w = zraw[lane*4+j];
    u32 hb = (w >> 8) & 0x7F;
    c += (hb >= 0x38 && hb <= 0x41) ? 1 : 0;
  }
  return __popcll(__ballot(c >= 2)) >= 32;
}
__device__ __forceinline__ int detect_i64(const int* __restrict__ ei_raw){
  int lane = threadIdx.x & 63;
  int c = 0;
  #pragma unroll
  for(int j=0;j<4;j++) c += (ei_raw[2*(lane*4+j)+1] == 0) ? 1 : 0;
  return __popcll(__ballot(c >= 3)) >= 32;
}

// ---------- K1: fused init + weight prep ----------
__global__ void k_prep(const u32* __restrict__ zraw, const void* __restrict__ pos_in,
    const void* __restrict__ mlp1_w, const void* __restrict__ mlp1_b,
    const void* __restrict__ mlp2_w, const void* __restrict__ mlp2_b,
    const void* __restrict__ lin1_w, const void* __restrict__ lin2_w,
    const void* __restrict__ lin2_b, const void* __restrict__ lin_w,
    const void* __restrict__ lin_b,  const void* __restrict__ coord_w,
    const void* __restrict__ coord_b,
    float* __restrict__ h, float* __restrict__ pos, int* __restrict__ wmaxi,
    float* __restrict__ b1f, float* __restrict__ b2v,
    float* __restrict__ w1t, float* __restrict__ w2t,
    float* __restrict__ l1t, u16* __restrict__ l1b, u16* __restrict__ l2b,
    float* __restrict__ l2bf, u16* __restrict__ lwb,
    float* __restrict__ lbf, float* __restrict__ cwf, float* __restrict__ cbf)
{
  int bf = detect_bf(zraw);
  int b = blockIdx.x;
  if(b < NN*HH/256){
    int i = b*256 + threadIdx.x;
    h[i] = ldin(zraw, i, bf);
    if(i < NN*3) pos[i] = ldin(pos_in, i, bf);
    if(i == 0) *wmaxi = 0;
  } else {
    int i = (b - NN*HH/256)*256 + threadIdx.x;    // < NL*NF*NF
    if(i < NL*NF){
      b1f[i]  = ldin(mlp1_b, i, bf);
      b2v[i]  = ldin(mlp2_b, i, bf);
      l2bf[i] = ldin(lin2_b, i, bf);
      lbf[i]  = ldin(lin_b,  i, bf);
    }
    if(i < NL*GG*NF){                             // w1t[l][g][f]
      int l = i/(GG*NF), rem = i%(GG*NF);
      int g = rem/NF, f = rem%NF;
      w1t[i] = ldin(mlp1_w, (l*NF + f)*GG + g, bf);
    }
    if(i < NL*NF*NF){
      int l = i/(NF*NF), rem = i%(NF*NF);
      int k = rem/NF, f = rem%NF;
      w2t[i] = ldin(mlp2_w, l*NF*NF + f*NF + k, bf);
      l1t[i] = ldin(lin1_w, l*NF*HH + f*HH + k, bf);
      l1b[i] = f2us(ldin(lin1_w, i, bf));         // row-major bf16 (MFMA B)
      l2b[i] = f2us(ldin(lin2_w, i, bf));
      lwb[i] = f2us(ldin(lin_w,  i, bf));
    }
    if(i < NL*(GG+2*HH)) cwf[i] = ldin(coord_w, i, bf);
    if(i < NL) cbf[i] = ldin(coord_b, i, bf);
  }
}

// ---------- K2: decode ei, distances, LDS histograms -> u16 partials ----------
__global__ void k_count(const int* __restrict__ ei_raw, const float* __restrict__ pos,
                        int* __restrict__ eiN, float* __restrict__ wE,
                        u32* __restrict__ partR32, u32* __restrict__ partC32,
                        int* __restrict__ wmaxi){
  __shared__ u32 hr[NN/2];
  __shared__ u32 hc[NN/2];
  int is64 = detect_i64(ei_raw);
  int b = blockIdx.x, tid = threadIdx.x;          // grid: NB x 256
  for(int i=tid; i<NN/2; i+=256){ hr[i]=0; hc[i]=0; }
  __syncthreads();
  int e0 = b*(EE/NB), e1 = e0 + EE/NB;
  float wm = 0.f;
  for(int e = e0 + tid; e < e1; e += 256){
    int r = is64 ? ei_raw[2*e] : ei_raw[e];
    int c = is64 ? ei_raw[2*(EE+e)] : ei_raw[EE+e];
    eiN[e] = r; eiN[EE+e] = c;
    float dx = pos[r*3+0]-pos[c*3+0];
    float dy = pos[r*3+1]-pos[c*3+1];
    float dz = pos[r*3+2]-pos[c*3+2];
    float w = sqrtf(dx*dx + dy*dy + dz*dz);
    wE[e] = w;
    wm = fmaxf(wm, w);
    atomicAdd(&hr[r>>1], (r&1) ? 0x10000u : 1u);
    atomicAdd(&hc[c>>1], (c&1) ? 0x10000u : 1u);
  }
  #pragma unroll
  for(int s=32; s>0; s>>=1) wm = fmaxf(wm, __shfl_down(wm, s, 64));
  if((tid & 63) == 0) atomicMax(wmaxi, __float_as_int(wm));
  __syncthreads();
  for(int i=tid; i<NN/2; i+=256){
    partR32[(size_t)b*(NN/2) + i] = hr[i];
    partC32[(size_t)b*(NN/2) + i] = hc[i];
  }
}

// ---------- K3: u16 partials -> exclusive block-prefixes + totals ----------
__global__ void k_sumpref(u16* __restrict__ partR16, u16* __restrict__ partC16,
                          int* __restrict__ degR, int* __restrict__ degC){
  int n = blockIdx.x*256 + threadIdx.x;
  if(n >= NN) return;
  u32 rr = 0, rc = 0;
  for(int b=0; b<NB; b++){
    u32 vr = partR16[(size_t)b*NN + n], vc = partC16[(size_t)b*NN + n];
    partR16[(size_t)b*NN + n] = (u16)rr;
    partC16[(size_t)b*NN + n] = (u16)rc;
    rr += vr; rc += vc;
  }
  degR[n] = (int)rr; degC[n] = (int)rc;
}

// ---------- K4: fused dual exclusive scan ----------
__global__ void k_scan2(const int* __restrict__ col_deg, const int* __restrict__ deg_row,
                        int* __restrict__ col_start, int* __restrict__ row_start){
  __shared__ int part[1024];
  int tid = threadIdx.x;
  const int CH = (NN + 1023)/1024;
  for(int pass=0; pass<2; pass++){
    const int* deg = pass ? deg_row : col_deg;
    int* start = pass ? row_start : col_start;
    int base = tid*CH;
    int s = 0;
    for(int i=0;i<CH;i++){ int idx=base+i; if(idx<NN) s += deg[idx]; }
    part[tid] = s;
    __syncthreads();
    for(int off=1; off<1024; off<<=1){
      int v = (tid>=off) ? part[tid-off] : 0;
      __syncthreads();
      part[tid] += v;
      __syncthreads();
    }
    int run = (tid==0) ? 0 : part[tid-1];
    for(int i=0;i<CH;i++){
      int idx = base+i;
      if(idx<NN){ start[idx]=run; run += deg[idx]; }
    }
    if(tid==1023) start[NN] = run;
    __syncthreads();
  }
}

// ---------- K5a: CSR fill via LDS rank histograms ----------
__global__ void k_fill(const int* __restrict__ eiN, const float* __restrict__ wE,
                       const int* __restrict__ col_start, const int* __restrict__ row_start,
                       const u16* __restrict__ partR16, const u16* __restrict__ partC16,
                       int* __restrict__ row_s, float* __restrict__ wEs,
                       int* __restrict__ rcol_s, float* __restrict__ rw_s){
  __shared__ u32 hr[NN/2];
  __shared__ u32 hc[NN/2];
  int b = blockIdx.x, t = threadIdx.x;
  for(int i=t; i<NN/2; i+=256){ hr[i]=0; hc[i]=0; }
  __syncthreads();
  int e0 = b*(EE/NB), e1 = e0 + EE/NB;
  for(int e = e0 + t; e < e1; e += 256){
    int r = eiN[e], c = eiN[EE+e];
    float w = wE[e];
    u32 oldc = atomicAdd(&hc[c>>1], (c&1) ? 0x10000u : 1u);
    u32 rkc = (c&1) ? (oldc >> 16) : (oldc & 0xFFFFu);
    int p = col_start[c] + (int)partC16[(size_t)b*NN + c] + (int)rkc;
    row_s[p] = r; wEs[p] = w;
    u32 oldr = atomicAdd(&hr[r>>1], (r&1) ? 0x10000u : 1u);
    u32 rkr = (r&1) ? (oldr >> 16) : (oldr & 0xFFFFu);
    int p2 = row_start[r] + (int)partR16[(size_t)b*NN + r] + (int)rkr;
    rcol_s[p2] = c; rw_s[p2] = w;
  }
}

// ---------- K5b: table build+pack (blocks 0..NL*128-1) + layer-0 node (rest) ----------
__global__ void k_tabnode(const float* __restrict__ w1t, const float* __restrict__ b1f,
                          const float* __restrict__ w2t, const float* __restrict__ b2v,
                          const float* __restrict__ cwf, const int* __restrict__ wmaxi,
                          u32* __restrict__ tabGb, float* __restrict__ tabS,
                          const float* __restrict__ h, const float* __restrict__ l1t,
                          u16* __restrict__ xfb, float* __restrict__ d_r,
                          float* __restrict__ d_c){
  __shared__ float attr[17*64];                   // 4.25 KB
  __shared__ float tls[128*19];                   // 9.5 KB
  int b = blockIdx.x, t = threadIdx.x;
  if(b < NL*128){
    int l = b >> 7;
    int r0 = (b & 127)*16;
    int f = t & 127, half = t >> 7;
    float delta = __int_as_float(*wmaxi) / (float)(TROWS-1);
    for(int idx=t; idx<17*64; idx+=256){
      int r = idx >> 6, g = idx & 63;
      int row = min(r0 + r, TROWS-1);
      float w = (float)row*delta;
      float d = w - (float)g*(10.f/49.f);
      attr[idx] = (g < GG) ? __expf(-12.005f*d*d) : 0.f;
    }
    __syncthreads();
    const float* __restrict__ w1 = w1t + l*GG*NF;
    float b1 = b1f[l*NF + f];
    float a1[9];
    #pragma unroll
    for(int r=0;r<9;r++) a1[r] = b1;
    for(int g=0; g<GG; g++){
      float wv = w1[g*NF + f];
      #pragma unroll
      for(int r=0;r<9;r++) a1[r] += attr[(half*8 + r)*64 + g]*wv;
    }
    #pragma unroll
    for(int r=0;r<9;r++) tls[f*19 + half*9 + r] = sspf(a1[r]);
    __syncthreads();
    const float* __restrict__ w2 = w2t + l*NF*NF;
    float b2 = b2v[l*NF + f];
    float a2[9];
    #pragma unroll
    for(int r=0;r<9;r++) a2[r] = b2;
    for(int k=0;k<NF;k++){
      float wv = w2[k*NF + f];
      #pragma unroll
      for(int r=0;r<9;r++) a2[r] += tls[k*19 + half*9 + r]*wv;
    }
    float v[9];
    #pragma unroll
    for(int r=0;r<9;r++){
      int row = min(r0 + half*8 + r, TROWS-1);
      float w = (float)row*delta;
      float C = 0.5f*(cosf(w*0.3141592653589793f) + 1.f);
      v[r] = a2[r]*C;
    }
    #pragma unroll
    for(int j=0;j<8;j++){
      int row = r0 + half*8 + j;
      tabGb[((size_t)l*TROWS + row)*NF + f] = (u32)f2us(v[j]) | ((u32)f2us(v[j+1]) << 16);
    }
    if(t < 16){
      const float* __restrict__ cwg = cwf + l*(GG+2*HH);
      float s = 0.f;
      for(int g=0; g<GG; g++) s += attr[t*64 + g]*cwg[g];
      tabS[l*TROWS + r0 + t] = s;
    }
  } else {
    int nb = b - NL*128;
    if(nb < NN/8){
      int f = t & 127, g = t >> 7;
      int n0 = nb*8 + g*4;
      const float* __restrict__ wt = l1t;         // l=0 [k][f]
      float acc[4] = {0.f,0.f,0.f,0.f};
      for(int k=0;k<HH;k++){
        float wv = wt[k*NF + f];
        #pragma unroll
        for(int i=0;i<4;i++) acc[i] += h[(n0+i)*HH + k]*wv;
      }
      #pragma unroll
      for(int i=0;i<4;i++) xfb[(n0+i)*NF + f] = f2us(acc[i]);
    } else {
      int lane = t & 63;
      int n = (nb - NN/8)*4 + (t >> 6);
      const float* __restrict__ cw = cwf;         // l=0
      float h0 = h[n*HH + lane], h1 = h[n*HH + 64 + lane];
      float ar = h0*cw[GG + lane]      + h1*cw[GG + 64 + lane];
      float ac = h0*cw[GG + HH + lane] + h1*cw[GG + HH + 64 + lane];
      #pragma unroll
      for(int s=32; s>0; s>>=1){
        ar += __shfl_down(ar, s, 64);
        ac += __shfl_down(ac, s, 64);
      }
      if(lane == 0){ d_r[n] = ar; d_c[n] = ac; }
    }
  }
}

// ---------- per-layer fused kernel: blocks 0..NN/16-1 = gather->LDS->MFMA
// update chain (GEMM1 lin2+ssp, GEMM2 lin +h, GEMM3 lin1(l+1)) + dots;
// blocks NN/16.. = coordagg (8 nodes/block). 512 threads.
// Frag layouts (round-3/11 validated): A[m=lane&15][k=quad*8+j] (LDS stride
// 136 u16), B[n=lane&15][k] row-major bf16, D col=lane&15(N), row=quad*4+r(M).
__global__ void k_layer(const int* __restrict__ col_start, const int* __restrict__ row_s,
                        const float* __restrict__ wEs, const u32* __restrict__ xfb32,
                        const u32* __restrict__ tabGb, const int* __restrict__ wmaxi,
                        int l,
                        const u16* __restrict__ l2b, const float* __restrict__ l2bf,
                        const u16* __restrict__ lwb, const float* __restrict__ lbf,
                        float* __restrict__ h, const u16* __restrict__ l1b,
                        const float* __restrict__ cwf, u16* __restrict__ xfb,
                        float* __restrict__ d_r, float* __restrict__ d_c,
                        const int* __restrict__ row_start, const int* __restrict__ rcol_s,
                        const float* __restrict__ rw_s, const float* __restrict__ tabS,
                        const float* __restrict__ cbf,
                        const float* __restrict__ pA, float* __restrict__ pB,
                        const u32* __restrict__ zraw, void* __restrict__ out){
  __shared__ __align__(16) u16 T[16*136];         // agg / h_new (4.25 KB)
  __shared__ __align__(16) u16 T2[16*136];        // sg          (4.25 KB)
  int b = blockIdx.x, t = threadIdx.x;
  float invD = (float)(TROWS-1) / __int_as_float(*wmaxi);
  int wave = t >> 6, lane = t & 63;

  if(b < NN/16){
    int n0 = b*16;
    // ---- gather: wave w -> nodes n0+2w, n0+2w+1; lane = feature pair ----
    {
      const u32* __restrict__ tg = tabGb + (size_t)l*TROWS*NF;
      u32* __restrict__ T32 = (u32*)T;
      #pragma unroll
      for(int j=0;j<2;j++){
        int n = n0 + wave*2 + j;
        int p0 = col_start[n], p1 = col_start[n+1];
        float aa[4] = {0.f,0.f,0.f,0.f};
        float bb[4] = {0.f,0.f,0.f,0.f};
        int p = p0;
        for(; p+4 <= p1; p += 4){
          #pragma unroll
          for(int k=0;k<4;k++){
            int r = row_s[p+k];
            float tf = wEs[p+k]*invD;
            int i0 = min((int)tf, TROWS-2);
            float fr = tf - (float)i0;
            uint2 pr = *(const uint2*)&tg[i0*NF + 2*lane];
            u32 x = xfb32[r*64 + lane];
            float lo = us2f((u16)pr.x), hi = us2f((u16)(pr.x>>16));
            aa[k] += us2f((u16)x)      *(lo + (hi-lo)*fr);
            lo = us2f((u16)pr.y); hi = us2f((u16)(pr.y>>16));
            bb[k] += us2f((u16)(x>>16))*(lo + (hi-lo)*fr);
          }
        }
        for(; p < p1; p++){
          int r = row_s[p];
          float tf = wEs[p]*invD;
          int i0 = min((int)tf, TROWS-2);
          float fr = tf - (float)i0;
          uint2 pr = *(const uint2*)&tg[i0*NF + 2*lane];
          u32 x = xfb32[r*64 + lane];
          float lo = us2f((u16)pr.x), hi = us2f((u16)(pr.x>>16));
          aa[0] += us2f((u16)x)      *(lo + (hi-lo)*fr);
          lo = us2f((u16)pr.y); hi = us2f((u16)(pr.y>>16));
          bb[0] += us2f((u16)(x>>16))*(lo + (hi-lo)*fr);
        }
        float av = (aa[0]+aa[1])+(aa[2]+aa[3]);
        float bv = (bb[0]+bb[1])+(bb[2]+bb[3]);
        T32[(wave*2+j)*68 + lane] = (u32)f2us(av) | ((u32)f2us(bv) << 16);
      }
    }
    __syncthreads();
    int m16 = lane & 15, quad = lane >> 4;
    int fcol = wave*16 + m16;                     // this wave's N-tile feature
    f32x4 acc;
    // ---- GEMM1: sg = ssp(agg @ lin2^T + b) ----
    {
      bf16x8 aA[4];
      #pragma unroll
      for(int ks=0; ks<4; ks++)
        aA[ks] = *(const bf16x8*)&T[m16*136 + ks*32 + quad*8];
      const u16* __restrict__ wA = l2b + l*HH*NF;
      float bv = l2bf[l*HH + fcol];
      acc = (f32x4){bv,bv,bv,bv};
      #pragma unroll
      for(int ks=0; ks<4; ks++){
        bf16x8 bb = *(const bf16x8*)&wA[fcol*NF + ks*32 + quad*8];
        acc = __builtin_amdgcn_mfma_f32_16x16x32_bf16(aA[ks], bb, acc, 0,0,0);
      }
      #pragma unroll
      for(int r=0;r<4;r++)
        T2[(quad*4+r)*136 + fcol] = f2us(sspf(acc[r]));
    }
    __syncthreads();
    // ---- GEMM2: hv = h + sg @ lin^T + b ----
    float hv[4];
    int bf = (l == NL-1) ? detect_bf(zraw) : 0;
    {
      bf16x8 aS[4];
      #pragma unroll
      for(int ks=0; ks<4; ks++)
        aS[ks] = *(const bf16x8*)&T2[m16*136 + ks*32 + quad*8];
      const u16* __restrict__ wB = lwb + l*HH*HH;
      float bv = lbf[l*HH + fcol];
      acc = (f32x4){bv,bv,bv,bv};
      #pragma unroll
      for(int ks=0; ks<4; ks++){
        bf16x8 bb = *(const bf16x8*)&wB[fcol*HH + ks*32 + quad*8];
        acc = __builtin_amdgcn_mfma_f32_16x16x32_bf16(aS[ks], bb, acc, 0,0,0);
      }
      #pragma unroll
      for(int r=0;r<4;r++)
        hv[r] = h[(n0+quad*4+r)*HH + fcol] + acc[r];
    }
    if(l == NL-1){
      #pragma unroll
      for(int r=0;r<4;r++){
        int n = n0 + quad*4 + r;
        if(bf) ((u16*)out)[NN*3 + n*HH + fcol] = f2us(hv[r]);
        else   ((float*)out)[NN*3 + n*HH + fcol] = hv[r];
      }
      return;
    }
    #pragma unroll
    for(int r=0;r<4;r++){
      int n = n0 + quad*4 + r;
      h[n*HH + fcol] = hv[r];
      T[(quad*4+r)*136 + fcol] = f2us(hv[r]);     // h_new (T reuse: safe, all
    }                                             // reads of T(agg) done pre-sync2)
    __syncthreads();
    // ---- GEMM3: xf(l+1) = h_new @ lin1^T ----
    {
      bf16x8 aH[4];
      #pragma unroll
      for(int ks=0; ks<4; ks++)
        aH[ks] = *(const bf16x8*)&T[m16*136 + ks*32 + quad*8];
      const u16* __restrict__ wC = l1b + (l+1)*NF*HH;
      acc = (f32x4){0.f,0.f,0.f,0.f};
      #pragma unroll
      for(int ks=0; ks<4; ks++){
        bf16x8 bb = *(const bf16x8*)&wC[fcol*HH + ks*32 + quad*8];
        acc = __builtin_amdgcn_mfma_f32_16x16x32_bf16(aH[ks], bb, acc, 0,0,0);
      }
      #pragma unroll
      for(int r=0;r<4;r++)
        xfb[(n0+quad*4+r)*NF + fcol] = f2us(acc[r]);
    }
    // ---- coord dots(l+1) from h_new in T (32 threads/node) ----
    {
      const float* __restrict__ cw = cwf + (l+1)*(GG + 2*HH);
      int j = t >> 5, l32 = t & 31;
      float ar = 0.f, ac = 0.f;
      #pragma unroll
      for(int i=0;i<4;i++){
        float hvv = us2f(T[j*136 + l32 + 32*i]);
        ar += hvv*cw[GG + l32 + 32*i];
        ac += hvv*cw[GG + HH + l32 + 32*i];
      }
      #pragma unroll
      for(int s=16; s>0; s>>=1){
        ar += __shfl_down(ar, s, 32);
        ac += __shfl_down(ac, s, 32);
      }
      if(l32 == 0){ d_r[n0+j] = ar; d_c[n0+j] = ac; }
    }
  } else {
    // ---- coordagg: 8 nodes/block (wave per node) ----
    int bf = (l == NL-1) ? detect_bf(zraw) : 0;
    int n = (b - NN/16)*8 + wave;
    const float* __restrict__ ts = tabS + l*TROWS;
    float cb = cbf[l] + d_r[n];
    int p0 = row_start[n], p1 = row_start[n+1];
    float px = pA[n*3+0], py = pA[n*3+1], pz = pA[n*3+2];
    float sx=0.f, sy=0.f, sz=0.f;
    for(int p = p0 + lane; p < p1; p += 64){
      int c = rcol_s[p];
      float tf = rw_s[p]*invD;
      int i0 = min((int)tf, TROWS-2);
      float fr = tf - (float)i0;
      float s0 = ts[i0], s1 = ts[i0+1];
      float acc = cb + d_c[c] + s0 + (s1-s0)*fr;
      sx += (px - pA[c*3+0])*acc;
      sy += (py - pA[c*3+1])*acc;
      sz += (pz - pA[c*3+2])*acc;
    }
    #pragma unroll
    for(int s=32; s>0; s>>=1){
      sx += __shfl_down(sx, s, 64);
      sy += __shfl_down(sy, s, 64);
      sz += __shfl_down(sz, s, 64);
    }
    if(lane == 0){
      int cnt = p1 - p0;
      float inv = (cnt > 0) ? 1.f/(float)cnt : 0.f;
      float ox = px + sx*inv, oy = py + sy*inv, oz = pz + sz*inv;
      if(l == NL-1){
        if(bf){
          u16* o = (u16*)out;
          o[n*3+0] = f2us(ox); o[n*3+1] = f2us(oy); o[n*3+2] = f2us(oz);
        } else {
          float* o = (float*)out;
          o[n*3+0] = ox; o[n*3+1] = oy; o[n*3+2] = oz;
        }
      } else {
        pB[n*3+0] = ox; pB[n*3+1] = oy; pB[n*3+2] = oz;
      }
    }
  }
}

extern "C" void kernel_launch(void* const* d_in, const int* in_sizes, int n_in,
                              void* d_out, int out_size, void* d_ws, size_t ws_size,
                              hipStream_t stream){
  const u32*  z      = (const u32*)d_in[0];
  const void* pos_in = d_in[1];
  const int*  ei_raw = (const int*)d_in[2];
  const void* mlp1_w = d_in[3];
  const void* mlp1_b = d_in[4];
  const void* mlp2_w = d_in[5];
  const void* mlp2_b = d_in[6];
  const void* lin1_w = d_in[7];
  const void* lin2_w = d_in[8];
  const void* lin2_b = d_in[9];
  const void* lin_w  = d_in[10];
  const void* lin_b  = d_in[11];
  const void* coord_w= d_in[12];
  const void* coord_b= d_in[13];

  float* W = (float*)d_ws;
  float* h    = W; W += NN*HH;
  float* posA = W; W += NN*3;
  float* posB = W; W += NN*3;
  float* d_r  = W; W += NN;
  float* d_c  = W; W += NN;
  float* wE   = W; W += EE;
  float* wEs  = W; W += EE;
  float* rw_s = W; W += EE;
  float* b1f  = W; W += NL*NF;
  float* b2v  = W; W += NL*NF;
  float* w1t  = W; W += NL*GG*NF;
  float* w2t  = W; W += NL*NF*NF;
  float* l1t  = W; W += NL*NF*HH;
  float* l2bf = W; W += NL*HH;
  float* lbf  = W; W += NL*HH;
  float* cwf  = W; W += NL*(GG+2*HH);
  float* cbf  = W; W += NL;
  W = (float*)(((uintptr_t)W + 63) & ~(uintptr_t)63);
  u32*  tabGb = (u32*)W; W += (size_t)NL*TROWS*NF;
  float* tabS = W; W += NL*TROWS;
  u16* l1b = (u16*)W; W += (NL*NF*NF)/2;
  u16* l2b = (u16*)W; W += (NL*NF*NF)/2;
  u16* lwb = (u16*)W; W += (NL*NF*NF)/2;
  u16* xfb = (u16*)W; W += (NN*NF)/2;
  u16* partR16 = (u16*)W; W += (size_t)NB*NN/2;
  u16* partC16 = (u16*)W; W += (size_t)NB*NN/2;
  int* degR      = (int*)W; W += NN;
  int* degC      = (int*)W; W += NN;
  int* col_start = (int*)W; W += NN+1;
  int* row_start = (int*)W; W += NN+1;
  int* row_s     = (int*)W; W += EE;
  int* rcol_s    = (int*)W; W += EE;
  int* eiN       = (int*)W; W += 2*EE;
  int* wmaxi     = (int*)W; W += 1;

  k_prep<<<NN*HH/256 + NL*NF*NF/256, 256, 0, stream>>>(
      z, pos_in, mlp1_w, mlp1_b, mlp2_w, mlp2_b, lin1_w, lin2_w, lin2_b,
      lin_w, lin_b, coord_w, coord_b,
      h, posA, wmaxi,
      b1f, b2v, w1t, w2t, l1t, l1b, l2b, l2bf, lwb, lbf, cwf, cbf);
  k_count<<<NB, 256, 0, stream>>>(ei_raw, posA, eiN, wE,
                                  (u32*)partR16, (u32*)partC16, wmaxi);
  k_sumpref<<<(NN+255)/256, 256, 0, stream>>>(partR16, partC16, degR, degC);
  k_scan2<<<1, 1024, 0, stream>>>(degC, degR, col_start, row_start);
  k_fill<<<NB, 256, 0, stream>>>(eiN, wE, col_start, row_start, partR16, partC16,
                                 row_s, wEs, rcol_s, rw_s);
  k_tabnode<<<NL*128 + NN/8 + NN/4, 256, 0, stream>>>(
      w1t, b1f, w2t, b2v, cwf, wmaxi, tabGb, tabS,
      h, l1t, xfb, d_r, d_c);

  float* pA = posA;
  float* pB = posB;
  for(int l=0; l<NL; l++){
    k_layer<<<NN/16 + NN/8, 512, 0, stream>>>(
        col_start, row_s, wEs, (const u32*)xfb, tabGb, wmaxi, l,
        l2b, l2bf, lwb, lbf, h, l1b, cwf, xfb, d_r, d_c,
        row_start, rcol_s, rw_s, tabS, cbf, pA, pB, z, d_out);
    float* tmp = pA; pA = pB; pB = tmp;
  }
}

// Round 14
// 410.433 us; speedup vs baseline: 2.0203x; 1.0092x over previous
//
#include <hip/hip_runtime.h>

// SchNet on MI355X — round 14: revert cooperative mega-kernel (launch fails in
// this harness -> zero output). Back to round-12 per-layer k_layer dispatches,
// KEEPING the race fix: parity ping-pong on xfb / d_r / d_c so update blocks
// (write l+1) never collide with gather/coordagg blocks (read l) within one
// dispatch. Table-based edge MLP + atomic-free CSR + MFMA update retained.

#define NN 10000
#define EE 320000
#define HH 128
#define GG 50
#define NF 128
#define NL 6
#define TROWS 2048
#define NB 128          // histogram blocks; EE/NB = 2500 edges each (fits u16)

typedef unsigned short u16;
typedef unsigned int u32;
typedef short bf16x8 __attribute__((ext_vector_type(8)));
typedef float f32x4  __attribute__((ext_vector_type(4)));

__device__ __forceinline__ float us2f(u16 u){
  union { float f; u32 i; } v; v.i = ((u32)u) << 16; return v.f;
}
__device__ __forceinline__ u16 f2us(float x){
  union { float f; u32 i; } v; v.f = x;
  u32 r = v.i + 0x7fffu + ((v.i >> 16) & 1u);   // RNE
  return (u16)(r >> 16);
}
__device__ __forceinline__ float ldin(const void* p, int i, int bf){
  return bf ? us2f(((const u16*)p)[i]) : ((const float*)p)[i];
}
__device__ __forceinline__ float sspf(float x){
  return fmaxf(x, 0.f) + __logf(1.f + __expf(-fabsf(x))) - 0.6931472f;
}
__device__ __forceinline__ int detect_bf(const u32* __restrict__ zraw){
  int lane = threadIdx.x & 63;
  int c = 0;
  #pragma unroll
  for(int j=0;j<4;j++){
    u32 w = zraw[lane*4+j];
    u32 hb = (w >> 8) & 0x7F;
    c += (hb >= 0x38 && hb <= 0x41) ? 1 : 0;
  }
  return __popcll(__ballot(c >= 2)) >= 32;
}
__device__ __forceinline__ int detect_i64(const int* __restrict__ ei_raw){
  int lane = threadIdx.x & 63;
  int c = 0;
  #pragma unroll
  for(int j=0;j<4;j++) c += (ei_raw[2*(lane*4+j)+1] == 0) ? 1 : 0;
  return __popcll(__ballot(c >= 3)) >= 32;
}

// ---------- K1: fused init + weight prep ----------
__global__ void k_prep(const u32* __restrict__ zraw, const void* __restrict__ pos_in,
    const void* __restrict__ mlp1_w, const void* __restrict__ mlp1_b,
    const void* __restrict__ mlp2_w, const void* __restrict__ mlp2_b,
    const void* __restrict__ lin1_w, const void* __restrict__ lin2_w,
    const void* __restrict__ lin2_b, const void* __restrict__ lin_w,
    const void* __restrict__ lin_b,  const void* __restrict__ coord_w,
    const void* __restrict__ coord_b,
    float* __restrict__ h, float* __restrict__ pos, int* __restrict__ wmaxi,
    float* __restrict__ b1f, float* __restrict__ b2v,
    float* __restrict__ w1t, float* __restrict__ w2t,
    float* __restrict__ l1t, u16* __restrict__ l1b, u16* __restrict__ l2b,
    float* __restrict__ l2bf, u16* __restrict__ lwb,
    float* __restrict__ lbf, float* __restrict__ cwf, float* __restrict__ cbf)
{
  int bf = detect_bf(zraw);
  int b = blockIdx.x;
  if(b < NN*HH/256){
    int i = b*256 + threadIdx.x;
    h[i] = ldin(zraw, i, bf);
    if(i < NN*3) pos[i] = ldin(pos_in, i, bf);
    if(i == 0) *wmaxi = 0;
  } else {
    int i = (b - NN*HH/256)*256 + threadIdx.x;    // < NL*NF*NF
    if(i < NL*NF){
      b1f[i]  = ldin(mlp1_b, i, bf);
      b2v[i]  = ldin(mlp2_b, i, bf);
      l2bf[i] = ldin(lin2_b, i, bf);
      lbf[i]  = ldin(lin_b,  i, bf);
    }
    if(i < NL*GG*NF){                             // w1t[l][g][f]
      int l = i/(GG*NF), rem = i%(GG*NF);
      int g = rem/NF, f = rem%NF;
      w1t[i] = ldin(mlp1_w, (l*NF + f)*GG + g, bf);
    }
    if(i < NL*NF*NF){
      int l = i/(NF*NF), rem = i%(NF*NF);
      int k = rem/NF, f = rem%NF;
      w2t[i] = ldin(mlp2_w, l*NF*NF + f*NF + k, bf);
      l1t[i] = ldin(lin1_w, l*NF*HH + f*HH + k, bf);
      l1b[i] = f2us(ldin(lin1_w, i, bf));         // row-major bf16 (MFMA B)
      l2b[i] = f2us(ldin(lin2_w, i, bf));
      lwb[i] = f2us(ldin(lin_w,  i, bf));
    }
    if(i < NL*(GG+2*HH)) cwf[i] = ldin(coord_w, i, bf);
    if(i < NL) cbf[i] = ldin(coord_b, i, bf);
  }
}

// ---------- K2: decode ei, distances, LDS histograms -> u16 partials ----------
__global__ void k_count(const int* __restrict__ ei_raw, const float* __restrict__ pos,
                        int* __restrict__ eiN, float* __restrict__ wE,
                        u32* __restrict__ partR32, u32* __restrict__ partC32,
                        int* __restrict__ wmaxi){
  __shared__ u32 hr[NN/2];
  __shared__ u32 hc[NN/2];
  int is64 = detect_i64(ei_raw);
  int b = blockIdx.x, tid = threadIdx.x;          // grid: NB x 256
  for(int i=tid; i<NN/2; i+=256){ hr[i]=0; hc[i]=0; }
  __syncthreads();
  int e0 = b*(EE/NB), e1 = e0 + EE/NB;
  float wm = 0.f;
  for(int e = e0 + tid; e < e1; e += 256){
    int r = is64 ? ei_raw[2*e] : ei_raw[e];
    int c = is64 ? ei_raw[2*(EE+e)] : ei_raw[EE+e];
    eiN[e] = r; eiN[EE+e] = c;
    float dx = pos[r*3+0]-pos[c*3+0];
    float dy = pos[r*3+1]-pos[c*3+1];
    float dz = pos[r*3+2]-pos[c*3+2];
    float w = sqrtf(dx*dx + dy*dy + dz*dz);
    wE[e] = w;
    wm = fmaxf(wm, w);
    atomicAdd(&hr[r>>1], (r&1) ? 0x10000u : 1u);
    atomicAdd(&hc[c>>1], (c&1) ? 0x10000u : 1u);
  }
  #pragma unroll
  for(int s=32; s>0; s>>=1) wm = fmaxf(wm, __shfl_down(wm, s, 64));
  if((tid & 63) == 0) atomicMax(wmaxi, __float_as_int(wm));
  __syncthreads();
  for(int i=tid; i<NN/2; i+=256){
    partR32[(size_t)b*(NN/2) + i] = hr[i];
    partC32[(size_t)b*(NN/2) + i] = hc[i];
  }
}

// ---------- K3: u16 partials -> exclusive block-prefixes + totals ----------
__global__ void k_sumpref(u16* __restrict__ partR16, u16* __restrict__ partC16,
                          int* __restrict__ degR, int* __restrict__ degC){
  int n = blockIdx.x*256 + threadIdx.x;
  if(n >= NN) return;
  u32 rr = 0, rc = 0;
  for(int b=0; b<NB; b++){
    u32 vr = partR16[(size_t)b*NN + n], vc = partC16[(size_t)b*NN + n];
    partR16[(size_t)b*NN + n] = (u16)rr;
    partC16[(size_t)b*NN + n] = (u16)rc;
    rr += vr; rc += vc;
  }
  degR[n] = (int)rr; degC[n] = (int)rc;
}

// ---------- K4: fused dual exclusive scan ----------
__global__ void k_scan2(const int* __restrict__ col_deg, const int* __restrict__ deg_row,
                        int* __restrict__ col_start, int* __restrict__ row_start){
  __shared__ int part[1024];
  int tid = threadIdx.x;
  const int CH = (NN + 1023)/1024;
  for(int pass=0; pass<2; pass++){
    const int* deg = pass ? deg_row : col_deg;
    int* start = pass ? row_start : col_start;
    int base = tid*CH;
    int s = 0;
    for(int i=0;i<CH;i++){ int idx=base+i; if(idx<NN) s += deg[idx]; }
    part[tid] = s;
    __syncthreads();
    for(int off=1; off<1024; off<<=1){
      int v = (tid>=off) ? part[tid-off] : 0;
      __syncthreads();
      part[tid] += v;
      __syncthreads();
    }
    int run = (tid==0) ? 0 : part[tid-1];
    for(int i=0;i<CH;i++){
      int idx = base+i;
      if(idx<NN){ start[idx]=run; run += deg[idx]; }
    }
    if(tid==1023) start[NN] = run;
    __syncthreads();
  }
}

// ---------- K5a: CSR fill via LDS rank histograms ----------
__global__ void k_fill(const int* __restrict__ eiN, const float* __restrict__ wE,
                       const int* __restrict__ col_start, const int* __restrict__ row_start,
                       const u16* __restrict__ partR16, const u16* __restrict__ partC16,
                       int* __restrict__ row_s, float* __restrict__ wEs,
                       int* __restrict__ rcol_s, float* __restrict__ rw_s){
  __shared__ u32 hr[NN/2];
  __shared__ u32 hc[NN/2];
  int b = blockIdx.x, t = threadIdx.x;
  for(int i=t; i<NN/2; i+=256){ hr[i]=0; hc[i]=0; }
  __syncthreads();
  int e0 = b*(EE/NB), e1 = e0 + EE/NB;
  for(int e = e0 + t; e < e1; e += 256){
    int r = eiN[e], c = eiN[EE+e];
    float w = wE[e];
    u32 oldc = atomicAdd(&hc[c>>1], (c&1) ? 0x10000u : 1u);
    u32 rkc = (c&1) ? (oldc >> 16) : (oldc & 0xFFFFu);
    int p = col_start[c] + (int)partC16[(size_t)b*NN + c] + (int)rkc;
    row_s[p] = r; wEs[p] = w;
    u32 oldr = atomicAdd(&hr[r>>1], (r&1) ? 0x10000u : 1u);
    u32 rkr = (r&1) ? (oldr >> 16) : (oldr & 0xFFFFu);
    int p2 = row_start[r] + (int)partR16[(size_t)b*NN + r] + (int)rkr;
    rcol_s[p2] = c; rw_s[p2] = w;
  }
}

// ---------- K5b: table build+pack + layer-0 node (writes parity-0 buffers) ----------
__global__ void k_tabnode(const float* __restrict__ w1t, const float* __restrict__ b1f,
                          const float* __restrict__ w2t, const float* __restrict__ b2v,
                          const float* __restrict__ cwf, const int* __restrict__ wmaxi,
                          u32* __restrict__ tabGb, float* __restrict__ tabS,
                          const float* __restrict__ h, const float* __restrict__ l1t,
                          u16* __restrict__ xfb0, float* __restrict__ dr0,
                          float* __restrict__ dc0){
  __shared__ float attr[17*64];
  __shared__ float tls[128*19];
  int b = blockIdx.x, t = threadIdx.x;
  if(b < NL*128){
    int l = b >> 7;
    int r0 = (b & 127)*16;
    int f = t & 127, half = t >> 7;
    float delta = __int_as_float(*wmaxi) / (float)(TROWS-1);
    for(int idx=t; idx<17*64; idx+=256){
      int r = idx >> 6, g = idx & 63;
      int row = min(r0 + r, TROWS-1);
      float w = (float)row*delta;
      float d = w - (float)g*(10.f/49.f);
      attr[idx] = (g < GG) ? __expf(-12.005f*d*d) : 0.f;
    }
    __syncthreads();
    const float* __restrict__ w1 = w1t + l*GG*NF;
    float b1 = b1f[l*NF + f];
    float a1[9];
    #pragma unroll
    for(int r=0;r<9;r++) a1[r] = b1;
    for(int g=0; g<GG; g++){
      float wv = w1[g*NF + f];
      #pragma unroll
      for(int r=0;r<9;r++) a1[r] += attr[(half*8 + r)*64 + g]*wv;
    }
    #pragma unroll
    for(int r=0;r<9;r++) tls[f*19 + half*9 + r] = sspf(a1[r]);
    __syncthreads();
    const float* __restrict__ w2 = w2t + l*NF*NF;
    float b2 = b2v[l*NF + f];
    float a2[9];
    #pragma unroll
    for(int r=0;r<9;r++) a2[r] = b2;
    for(int k=0;k<NF;k++){
      float wv = w2[k*NF + f];
      #pragma unroll
      for(int r=0;r<9;r++) a2[r] += tls[k*19 + half*9 + r]*wv;
    }
    float v[9];
    #pragma unroll
    for(int r=0;r<9;r++){
      int row = min(r0 + half*8 + r, TROWS-1);
      float w = (float)row*delta;
      float C = 0.5f*(cosf(w*0.3141592653589793f) + 1.f);
      v[r] = a2[r]*C;
    }
    #pragma unroll
    for(int j=0;j<8;j++){
      int row = r0 + half*8 + j;
      tabGb[((size_t)l*TROWS + row)*NF + f] = (u32)f2us(v[j]) | ((u32)f2us(v[j+1]) << 16);
    }
    if(t < 16){
      const float* __restrict__ cwg = cwf + l*(GG+2*HH);
      float s = 0.f;
      for(int g=0; g<GG; g++) s += attr[t*64 + g]*cwg[g];
      tabS[l*TROWS + r0 + t] = s;
    }
  } else {
    int nb = b - NL*128;
    if(nb < NN/8){
      int f = t & 127, g = t >> 7;
      int n0 = nb*8 + g*4;
      const float* __restrict__ wt = l1t;         // l=0 [k][f]
      float acc[4] = {0.f,0.f,0.f,0.f};
      for(int k=0;k<HH;k++){
        float wv = wt[k*NF + f];
        #pragma unroll
        for(int i=0;i<4;i++) acc[i] += h[(n0+i)*HH + k]*wv;
      }
      #pragma unroll
      for(int i=0;i<4;i++) xfb0[(n0+i)*NF + f] = f2us(acc[i]);
    } else {
      int lane = t & 63;
      int n = (nb - NN/8)*4 + (t >> 6);
      const float* __restrict__ cw = cwf;         // l=0
      float h0 = h[n*HH + lane], h1 = h[n*HH + 64 + lane];
      float ar = h0*cw[GG + lane]      + h1*cw[GG + 64 + lane];
      float ac = h0*cw[GG + HH + lane] + h1*cw[GG + HH + 64 + lane];
      #pragma unroll
      for(int s=32; s>0; s>>=1){
        ar += __shfl_down(ar, s, 64);
        ac += __shfl_down(ac, s, 64);
      }
      if(lane == 0){ dr0[n] = ar; dc0[n] = ac; }
    }
  }
}

// ---------- per-layer fused kernel (regular launch): blocks 0..NN/16-1 =
// gather->LDS->MFMA update chain + dots; blocks NN/16.. = coordagg.
// 512 threads. Parity ping-pong: reads xfR/drR/dcR (layer l), writes
// xfW/drW/dcW (layer l+1) — no intra-dispatch read/write aliasing.
__global__ void k_layer(const int* __restrict__ col_start, const int* __restrict__ row_s,
                        const float* __restrict__ wEs, const u32* __restrict__ xfR,
                        u16* __restrict__ xfW,
                        const u32* __restrict__ tabGb, const int* __restrict__ wmaxi,
                        int l,
                        const u16* __restrict__ l2b, const float* __restrict__ l2bf,
                        const u16* __restrict__ lwb, const float* __restrict__ lbf,
                        float* __restrict__ h, const u16* __restrict__ l1b,
                        const float* __restrict__ cwf,
                        const float* __restrict__ drR, float* __restrict__ drW,
                        const float* __restrict__ dcR, float* __restrict__ dcW,
                        const int* __restrict__ row_start, const int* __restrict__ rcol_s,
                        const float* __restrict__ rw_s, const float* __restrict__ tabS,
                        const float* __restrict__ cbf,
                        const float* __restrict__ pA, float* __restrict__ pB,
                        const u32* __restrict__ zraw, void* __restrict__ out){
  __shared__ __align__(16) u16 T[16*136];         // agg / h_new (4.25 KB)
  __shared__ __align__(16) u16 T2[16*136];        // sg          (4.25 KB)
  int b = blockIdx.x, t = threadIdx.x;
  float invD = (float)(TROWS-1) / __int_as_float(*wmaxi);
  int wave = t >> 6, lane = t & 63;

  if(b < NN/16){
    int n0 = b*16;
    // ---- gather: wave w -> nodes n0+2w, n0+2w+1; lane = feature pair ----
    {
      const u32* __restrict__ tg = tabGb + (size_t)l*TROWS*NF;
      u32* __restrict__ T32 = (u32*)T;
      #pragma unroll
      for(int j=0;j<2;j++){
        int n = n0 + wave*2 + j;
        int p0 = col_start[n], p1 = col_start[n+1];
        float aa[4] = {0.f,0.f,0.f,0.f};
        float bb[4] = {0.f,0.f,0.f,0.f};
        int p = p0;
        for(; p+4 <= p1; p += 4){
          #pragma unroll
          for(int k=0;k<4;k++){
            int r = row_s[p+k];
            float tf = wEs[p+k]*invD;
            int i0 = min((int)tf, TROWS-2);
            float fr = tf - (float)i0;
            uint2 pr = *(const uint2*)&tg[i0*NF + 2*lane];
            u32 x = xfR[r*64 + lane];
            float lo = us2f((u16)pr.x), hi = us2f((u16)(pr.x>>16));
            aa[k] += us2f((u16)x)      *(lo + (hi-lo)*fr);
            lo = us2f((u16)pr.y); hi = us2f((u16)(pr.y>>16));
            bb[k] += us2f((u16)(x>>16))*(lo + (hi-lo)*fr);
          }
        }
        for(; p < p1; p++){
          int r = row_s[p];
          float tf = wEs[p]*invD;
          int i0 = min((int)tf, TROWS-2);
          float fr = tf - (float)i0;
          uint2 pr = *(const uint2*)&tg[i0*NF + 2*lane];
          u32 x = xfR[r*64 + lane];
          float lo = us2f((u16)pr.x), hi = us2f((u16)(pr.x>>16));
          aa[0] += us2f((u16)x)      *(lo + (hi-lo)*fr);
          lo = us2f((u16)pr.y); hi = us2f((u16)(pr.y>>16));
          bb[0] += us2f((u16)(x>>16))*(lo + (hi-lo)*fr);
        }
        float av = (aa[0]+aa[1])+(aa[2]+aa[3]);
        float bv = (bb[0]+bb[1])+(bb[2]+bb[3]);
        T32[(wave*2+j)*68 + lane] = (u32)f2us(av) | ((u32)f2us(bv) << 16);
      }
    }
    __syncthreads();
    int m16 = lane & 15, quad = lane >> 4;
    int fcol = wave*16 + m16;                     // this wave's N-tile feature
    f32x4 acc;
    // ---- GEMM1: sg = ssp(agg @ lin2^T + b) ----
    {
      bf16x8 aA[4];
      #pragma unroll
      for(int ks=0; ks<4; ks++)
        aA[ks] = *(const bf16x8*)&T[m16*136 + ks*32 + quad*8];
      const u16* __restrict__ wA = l2b + l*HH*NF;
      float bv = l2bf[l*HH + fcol];
      acc = (f32x4){bv,bv,bv,bv};
      #pragma unroll
      for(int ks=0; ks<4; ks++){
        bf16x8 bb = *(const bf16x8*)&wA[fcol*NF + ks*32 + quad*8];
        acc = __builtin_amdgcn_mfma_f32_16x16x32_bf16(aA[ks], bb, acc, 0,0,0);
      }
      #pragma unroll
      for(int r=0;r<4;r++)
        T2[(quad*4+r)*136 + fcol] = f2us(sspf(acc[r]));
    }
    __syncthreads();
    // ---- GEMM2: hv = h + sg @ lin^T + b ----
    float hv[4];
    int bf = (l == NL-1) ? detect_bf(zraw) : 0;
    {
      bf16x8 aS[4];
      #pragma unroll
      for(int ks=0; ks<4; ks++)
        aS[ks] = *(const bf16x8*)&T2[m16*136 + ks*32 + quad*8];
      const u16* __restrict__ wB = lwb + l*HH*HH;
      float bv = lbf[l*HH + fcol];
      acc = (f32x4){bv,bv,bv,bv};
      #pragma unroll
      for(int ks=0; ks<4; ks++){
        bf16x8 bb = *(const bf16x8*)&wB[fcol*HH + ks*32 + quad*8];
        acc = __builtin_amdgcn_mfma_f32_16x16x32_bf16(aS[ks], bb, acc, 0,0,0);
      }
      #pragma unroll
      for(int r=0;r<4;r++)
        hv[r] = h[(n0+quad*4+r)*HH + fcol] + acc[r];
    }
    if(l == NL-1){
      #pragma unroll
      for(int r=0;r<4;r++){
        int n = n0 + quad*4 + r;
        if(bf) ((u16*)out)[NN*3 + n*HH + fcol] = f2us(hv[r]);
        else   ((float*)out)[NN*3 + n*HH + fcol] = hv[r];
      }
      return;
    }
    #pragma unroll
    for(int r=0;r<4;r++){
      int n = n0 + quad*4 + r;
      h[n*HH + fcol] = hv[r];
      T[(quad*4+r)*136 + fcol] = f2us(hv[r]);     // h_new (T reuse safe)
    }
    __syncthreads();
    // ---- GEMM3: xf(l+1) = h_new @ lin1^T -> parity-W buffer ----
    {
      bf16x8 aH[4];
      #pragma unroll
      for(int ks=0; ks<4; ks++)
        aH[ks] = *(const bf16x8*)&T[m16*136 + ks*32 + quad*8];
      const u16* __restrict__ wC = l1b + (l+1)*NF*HH;
      acc = (f32x4){0.f,0.f,0.f,0.f};
      #pragma unroll
      for(int ks=0; ks<4; ks++){
        bf16x8 bb = *(const bf16x8*)&wC[fcol*HH + ks*32 + quad*8];
        acc = __builtin_amdgcn_mfma_f32_16x16x32_bf16(aH[ks], bb, acc, 0,0,0);
      }
      #pragma unroll
      for(int r=0;r<4;r++)
        xfW[(n0+quad*4+r)*NF + fcol] = f2us(acc[r]);
    }
    // ---- coord dots(l+1) from h_new in T (32 threads/node) ----
    {
      const float* __restrict__ cw = cwf + (l+1)*(GG + 2*HH);
      int j = t >> 5, l32 = t & 31;
      float ar = 0.f, ac = 0.f;
      #pragma unroll
      for(int i=0;i<4;i++){
        float hvv = us2f(T[j*136 + l32 + 32*i]);
        ar += hvv*cw[GG + l32 + 32*i];
        ac += hvv*cw[GG + HH + l32 + 32*i];
      }
      #pragma unroll
      for(int s=16; s>0; s>>=1){
        ar += __shfl_down(ar, s, 32);
        ac += __shfl_down(ac, s, 32);
      }
      if(l32 == 0){ drW[n0+j] = ar; dcW[n0+j] = ac; }
    }
  } else {
    // ---- coordagg: 8 nodes/block (wave per node), reads parity-R dots ----
    int bf = (l == NL-1) ? detect_bf(zraw) : 0;
    int n = (b - NN/16)*8 + wave;
    const float* __restrict__ ts = tabS + l*TROWS;
    float cb = cbf[l] + drR[n];
    int p0 = row_start[n], p1 = row_start[n+1];
    float px = pA[n*3+0], py = pA[n*3+1], pz = pA[n*3+2];
    float sx=0.f, sy=0.f, sz=0.f;
    for(int p = p0 + lane; p < p1; p += 64){
      int c = rcol_s[p];
      float tf = rw_s[p]*invD;
      int i0 = min((int)tf, TROWS-2);
      float fr = tf - (float)i0;
      float s0 = ts[i0], s1 = ts[i0+1];
      float acc = cb + dcR[c] + s0 + (s1-s0)*fr;
      sx += (px - pA[c*3+0])*acc;
      sy += (py - pA[c*3+1])*acc;
      sz += (pz - pA[c*3+2])*acc;
    }
    #pragma unroll
    for(int s=32; s>0; s>>=1){
      sx += __shfl_down(sx, s, 64);
      sy += __shfl_down(sy, s, 64);
      sz += __shfl_down(sz, s, 64);
    }
    if(lane == 0){
      int cnt = p1 - p0;
      float inv = (cnt > 0) ? 1.f/(float)cnt : 0.f;
      float ox = px + sx*inv, oy = py + sy*inv, oz = pz + sz*inv;
      if(l == NL-1){
        if(bf){
          u16* o = (u16*)out;
          o[n*3+0] = f2us(ox); o[n*3+1] = f2us(oy); o[n*3+2] = f2us(oz);
        } else {
          float* o = (float*)out;
          o[n*3+0] = ox; o[n*3+1] = oy; o[n*3+2] = oz;
        }
      } else {
        pB[n*3+0] = ox; pB[n*3+1] = oy; pB[n*3+2] = oz;
      }
    }
  }
}

extern "C" void kernel_launch(void* const* d_in, const int* in_sizes, int n_in,
                              void* d_out, int out_size, void* d_ws, size_t ws_size,
                              hipStream_t stream){
  const u32*  z      = (const u32*)d_in[0];
  const void* pos_in = d_in[1];
  const int*  ei_raw = (const int*)d_in[2];
  const void* mlp1_w = d_in[3];
  const void* mlp1_b = d_in[4];
  const void* mlp2_w = d_in[5];
  const void* mlp2_b = d_in[6];
  const void* lin1_w = d_in[7];
  const void* lin2_w = d_in[8];
  const void* lin2_b = d_in[9];
  const void* lin_w  = d_in[10];
  const void* lin_b  = d_in[11];
  const void* coord_w= d_in[12];
  const void* coord_b= d_in[13];

  float* W = (float*)d_ws;
  float* h    = W; W += NN*HH;
  float* pos0 = W; W += NN*3;
  float* pos1 = W; W += NN*3;
  float* dr0  = W; W += NN;
  float* dr1  = W; W += NN;
  float* dc0  = W; W += NN;
  float* dc1  = W; W += NN;
  float* wE   = W; W += EE;
  float* wEs  = W; W += EE;
  float* rw_s = W; W += EE;
  float* b1f  = W; W += NL*NF;
  float* b2v  = W; W += NL*NF;
  float* w1t  = W; W += NL*GG*NF;
  float* w2t  = W; W += NL*NF*NF;
  float* l1t  = W; W += NL*NF*HH;
  float* l2bf = W; W += NL*HH;
  float* lbf  = W; W += NL*HH;
  float* cwf  = W; W += NL*(GG+2*HH);
  float* cbf  = W; W += NL;
  W = (float*)(((uintptr_t)W + 63) & ~(uintptr_t)63);
  u32*  tabGb = (u32*)W; W += (size_t)NL*TROWS*NF;
  float* tabS = W; W += NL*TROWS;
  u16* l1b  = (u16*)W; W += (NL*NF*NF)/2;
  u16* l2b  = (u16*)W; W += (NL*NF*NF)/2;
  u16* lwb  = (u16*)W; W += (NL*NF*NF)/2;
  u16* xfb0 = (u16*)W; W += (NN*NF)/2;
  u16* xfb1 = (u16*)W; W += (NN*NF)/2;
  u16* partR16 = (u16*)W; W += (size_t)NB*NN/2;
  u16* partC16 = (u16*)W; W += (size_t)NB*NN/2;
  int* degR      = (int*)W; W += NN;
  int* degC      = (int*)W; W += NN;
  int* col_start = (int*)W; W += NN+1;
  int* row_start = (int*)W; W += NN+1;
  int* row_s     = (int*)W; W += EE;
  int* rcol_s    = (int*)W; W += EE;
  int* eiN       = (int*)W; W += 2*EE;
  int* wmaxi     = (int*)W; W += 1;

  k_prep<<<NN*HH/256 + NL*NF*NF/256, 256, 0, stream>>>(
      z, pos_in, mlp1_w, mlp1_b, mlp2_w, mlp2_b, lin1_w, lin2_w, lin2_b,
      lin_w, lin_b, coord_w, coord_b,
      h, pos0, wmaxi,
      b1f, b2v, w1t, w2t, l1t, l1b, l2b, l2bf, lwb, lbf, cwf, cbf);
  k_count<<<NB, 256, 0, stream>>>(ei_raw, pos0, eiN, wE,
                                  (u32*)partR16, (u32*)partC16, wmaxi);
  k_sumpref<<<(NN+255)/256, 256, 0, stream>>>(partR16, partC16, degR, degC);
  k_scan2<<<1, 1024, 0, stream>>>(degC, degR, col_start, row_start);
  k_fill<<<NB, 256, 0, stream>>>(eiN, wE, col_start, row_start, partR16, partC16,
                                 row_s, wEs, rcol_s, rw_s);
  k_tabnode<<<NL*128 + NN/8 + NN/4, 256, 0, stream>>>(
      w1t, b1f, w2t, b2v, cwf, wmaxi, tabGb, tabS,
      h, l1t, xfb0, dr0, dc0);

  for(int l=0; l<NL; l++){
    int par = l & 1;
    const u32* xfR = (const u32*)(par ? xfb1 : xfb0);
    u16* xfW = par ? xfb0 : xfb1;
    const float* drR = par ? dr1 : dr0;  float* drW = par ? dr0 : dr1;
    const float* dcR = par ? dc1 : dc0;  float* dcW = par ? dc0 : dc1;
    const float* pA = par ? pos1 : pos0; float* pB = par ? pos0 : pos1;
    k_layer<<<NN/16 + NN/8, 512, 0, stream>>>(
        col_start, row_s, wEs, xfR, xfW, tabGb, wmaxi, l,
        l2b, l2bf, lwb, lbf, h, l1b, cwf,
        drR, drW, dcR, dcW,
        row_start, rcol_s, rw_s, tabS, cbf, pA, pB, z, d_out);
  }
}